// Round 1
// baseline (1091.456 us; speedup 1.0000x reference)
//
#include <hip/hip_runtime.h>
#include <stdint.h>

#define TT 2048
#define EE 2048
#define HH 16
#define DD 128

static constexpr float F_EPS = 1e-5f;
static constexpr float F_SCALING = (float)0.08838834764831845; // 128^-0.5

using f32x4  = __attribute__((ext_vector_type(4))) float;
using bf16x8 = __attribute__((ext_vector_type(8))) short;
using u16x8  = __attribute__((ext_vector_type(8))) unsigned short;

#define MFMA_BF16(a,b,c) __builtin_amdgcn_mfma_f32_16x16x32_bf16((a),(b),(c),0,0,0)

#define GLD16(gp, lp) __builtin_amdgcn_global_load_lds( \
    (__attribute__((address_space(1))) void*)(unsigned long long)(gp), \
    (__attribute__((address_space(3))) void*)(lp), 16, 0, 0)

__device__ __forceinline__ unsigned short f2bf(float x){
  unsigned u = __float_as_uint(x);
  u = (u + 0x7FFFu + ((u >> 16) & 1u)) >> 16;
  return (unsigned short)u;
}
__device__ __forceinline__ float bf2f(unsigned short h){
  return __uint_as_float(((unsigned)h) << 16);
}

// ---------------- row-wise quantization kernels ----------------
// one block per row (2048 cols, 256 threads => 8 elems/thread, kept in regs)

__global__ __launch_bounds__(256) void k_rowquant(
    const float* __restrict__ in, unsigned short* __restrict__ outq,
    float* __restrict__ outs, float qmax)
{
  const int row = blockIdx.x;
  const int tid = threadIdx.x;
  const float* r = in + (size_t)row * EE;
  float x[8];
  {
    const f32x4 a = *(const f32x4*)(r + tid*8);
    const f32x4 b = *(const f32x4*)(r + tid*8 + 4);
    x[0]=a[0]; x[1]=a[1]; x[2]=a[2]; x[3]=a[3];
    x[4]=b[0]; x[5]=b[1]; x[6]=b[2]; x[7]=b[3];
  }
  float am = 0.f;
  #pragma unroll
  for (int j=0;j<8;j++) am = fmaxf(am, fabsf(x[j]));
  #pragma unroll
  for (int o=1;o<64;o<<=1) am = fmaxf(am, __shfl_xor(am, o));
  __shared__ float red[4];
  if ((tid&63)==0) red[tid>>6] = am;
  __syncthreads();
  am = fmaxf(fmaxf(red[0],red[1]), fmaxf(red[2],red[3]));
  const float s = fmaxf(am, F_EPS) / qmax;
  if (tid==0) outs[row] = s;
  u16x8 qv;
  #pragma unroll
  for (int j=0;j<8;j++) qv[j] = f2bf(rintf(x[j]/s));   // |int|<=qmax exact in bf16
  *(u16x8*)(outq + (size_t)row*EE + tid*8) = qv;
}

// quantize + dequantize in place (for v = _quant_absmax_last(vraw))
__global__ __launch_bounds__(256) void k_quantdq_row(
    const float* __restrict__ in, float* __restrict__ out)
{
  const int row = blockIdx.x;
  const int tid = threadIdx.x;
  const float* r = in + (size_t)row * EE;
  float x[8];
  {
    const f32x4 a = *(const f32x4*)(r + tid*8);
    const f32x4 b = *(const f32x4*)(r + tid*8 + 4);
    x[0]=a[0]; x[1]=a[1]; x[2]=a[2]; x[3]=a[3];
    x[4]=b[0]; x[5]=b[1]; x[6]=b[2]; x[7]=b[3];
  }
  float am = 0.f;
  #pragma unroll
  for (int j=0;j<8;j++) am = fmaxf(am, fabsf(x[j]));
  #pragma unroll
  for (int o=1;o<64;o<<=1) am = fmaxf(am, __shfl_xor(am, o));
  __shared__ float red[4];
  if ((tid&63)==0) red[tid>>6] = am;
  __syncthreads();
  am = fmaxf(fmaxf(red[0],red[1]), fmaxf(red[2],red[3]));
  const float s = fmaxf(am, F_EPS) / 127.f;
  f32x4 o0, o1;
  o0[0]=rintf(x[0]/s)*s; o0[1]=rintf(x[1]/s)*s; o0[2]=rintf(x[2]/s)*s; o0[3]=rintf(x[3]/s)*s;
  o1[0]=rintf(x[4]/s)*s; o1[1]=rintf(x[5]/s)*s; o1[2]=rintf(x[6]/s)*s; o1[3]=rintf(x[7]/s)*s;
  *(f32x4*)(out + (size_t)row*EE + tid*8)     = o0;
  *(f32x4*)(out + (size_t)row*EE + tid*8 + 4) = o1;
}

// mixed K quantization: important rows -> 8-bit (mix eps rule), else 4-bit
__global__ __launch_bounds__(256) void k_quant_kmixed(
    const float* __restrict__ kin, const int* __restrict__ imp,
    unsigned short* __restrict__ qkm, float* __restrict__ sk)
{
  const int row = blockIdx.x;
  const int tid = threadIdx.x;
  const float* r = kin + (size_t)row * EE;
  float x[8];
  {
    const f32x4 a = *(const f32x4*)(r + tid*8);
    const f32x4 b = *(const f32x4*)(r + tid*8 + 4);
    x[0]=a[0]; x[1]=a[1]; x[2]=a[2]; x[3]=a[3];
    x[4]=b[0]; x[5]=b[1]; x[6]=b[2]; x[7]=b[3];
  }
  float am = 0.f;
  #pragma unroll
  for (int j=0;j<8;j++) am = fmaxf(am, fabsf(x[j]));
  #pragma unroll
  for (int o=1;o<64;o<<=1) am = fmaxf(am, __shfl_xor(am, o));
  __shared__ float red[4];
  if ((tid&63)==0) red[tid>>6] = am;
  __syncthreads();
  am = fmaxf(fmaxf(red[0],red[1]), fmaxf(red[2],red[3]));
  float s;
  if (imp[row]) s = fmaxf(am / 127.f, F_EPS);   // _fake_quant_mix
  else          s = fmaxf(am, F_EPS) / 7.f;     // _fake_quant_k4
  if (tid==0) sk[row] = s;
  u16x8 qv;
  #pragma unroll
  for (int j=0;j<8;j++) qv[j] = f2bf(rintf(x[j]/s));
  *(u16x8*)(qkm + (size_t)row*EE + tid*8) = qv;
}

// ---------------- GEMM: C[m,n] = post*(sa[m]*sb[n]*dot(Aq[m,:],Bq[n,:]) + bias[n]) ----
// Aq: MxK bf16-ints, Bq: NxK bf16-ints (dot over last dim). 128x128 tile, BK=64.
__global__ __launch_bounds__(256) void k_gemm(
    const unsigned short* __restrict__ Aq, const float* __restrict__ sa,
    const unsigned short* __restrict__ Bq, const float* __restrict__ sb,
    const float* __restrict__ bias, float post_scale,
    float* __restrict__ Cout, unsigned short* __restrict__ Hout,
    unsigned short* __restrict__ Lout)
{
  __shared__ unsigned short lA[128*64];
  __shared__ unsigned short lB[128*64];
  const int tid = threadIdx.x;
  const int bm = blockIdx.y, bn = blockIdx.x;
  const int lane = tid & 63, w = tid >> 6;
  const int wr = w >> 1, wc = w & 1;
  const int rA = tid >> 3;            // 0..31
  const int cA = (tid & 7) * 8;
  f32x4 acc[4][4];
  const f32x4 FZ = {0.f,0.f,0.f,0.f};
  #pragma unroll
  for (int i=0;i<4;i++)
    #pragma unroll
    for (int j=0;j<4;j++) acc[i][j] = FZ;

  const unsigned short* gA0 = Aq + (size_t)(bm*128 + rA)*EE + cA;
  const unsigned short* gB0 = Bq + (size_t)(bn*128 + rA)*EE + cA;
  unsigned short* lA0 = lA + tid*8;
  unsigned short* lB0 = lB + tid*8;

  for (int k0 = 0; k0 < EE; k0 += 64) {
    #pragma unroll
    for (int i=0;i<4;i++) GLD16(gA0 + (size_t)i*32*EE + k0, lA0 + i*2048);
    #pragma unroll
    for (int i=0;i<4;i++) GLD16(gB0 + (size_t)i*32*EE + k0, lB0 + i*2048);
    __syncthreads();
    #pragma unroll
    for (int kk=0;kk<2;kk++){
      bf16x8 af[4], bfr[4];
      #pragma unroll
      for (int mi=0;mi<4;mi++)
        af[mi] = *(const bf16x8*)(lA + (wr*64 + mi*16 + (lane&15))*64 + kk*32 + (lane>>4)*8);
      #pragma unroll
      for (int ni=0;ni<4;ni++)
        bfr[ni] = *(const bf16x8*)(lB + (wc*64 + ni*16 + (lane&15))*64 + kk*32 + (lane>>4)*8);
      #pragma unroll
      for (int mi=0;mi<4;mi++)
        #pragma unroll
        for (int ni=0;ni<4;ni++)
          acc[mi][ni] = MFMA_BF16(af[mi], bfr[ni], acc[mi][ni]);
    }
    __syncthreads();
  }
  const int row0 = bm*128 + wr*64;
  const int col0 = bn*128 + wc*64;
  #pragma unroll
  for (int mi=0;mi<4;mi++){
    #pragma unroll
    for (int r=0;r<4;r++){
      const int row = row0 + mi*16 + (lane>>4)*4 + r;
      const float sav = sa[row];
      #pragma unroll
      for (int ni=0;ni<4;ni++){
        const int col = col0 + ni*16 + (lane&15);
        const float v = (acc[mi][ni][r]*sav*sb[col] + bias[col]) * post_scale;
        if (Cout) Cout[(size_t)row*EE + col] = v;
        if (Hout){
          const unsigned short hh = f2bf(v);
          Hout[(size_t)row*EE + col] = hh;
          Lout[(size_t)row*EE + col] = f2bf(v - bf2f(hh));
        }
      }
    }
  }
}

// ---------------- V per-column quant ----------------
__global__ void k_init(unsigned* __restrict__ sv_bits, int* __restrict__ imp)
{
  const int i = blockIdx.x*256 + threadIdx.x;
  if (i < EE) sv_bits[i] = 0u;
  if (i < TT) imp[i] = 0;
}

__global__ __launch_bounds__(256) void k_colmax(
    const float* __restrict__ v, unsigned* __restrict__ sv_bits)
{
  const int e = blockIdx.x*256 + threadIdx.x;
  const int t0 = blockIdx.y*256;
  float am = 0.f;
  for (int t=t0; t<t0+256; ++t) am = fmaxf(am, fabsf(v[(size_t)t*EE + e]));
  atomicMax(sv_bits + e, __float_as_uint(am));   // positive floats: uint order == float order
}

// quantize V to int-bf16, store TRANSPOSED qvT[e][t]; also write sv[e]
__global__ __launch_bounds__(256) void k_vq_transpose(
    const float* __restrict__ v, const unsigned* __restrict__ sv_bits,
    float* __restrict__ sv, unsigned short* __restrict__ qvT)
{
  __shared__ unsigned short tile[64][66];
  const int t0 = blockIdx.x*64, e0 = blockIdx.y*64;
  const int tid = threadIdx.x;
  {
    const int ee = tid & 63, tb = (tid>>6)*16;
    const float sve = fmaxf(__uint_as_float(sv_bits[e0+ee]), F_EPS) / 127.f;
    for (int i=0;i<16;i++)
      tile[tb+i][ee] = f2bf(rintf(v[(size_t)(t0+tb+i)*EE + e0+ee] / sve));
  }
  if (blockIdx.x==0 && tid<64)
    sv[e0+tid] = fmaxf(__uint_as_float(sv_bits[e0+tid]), F_EPS) / 127.f;
  __syncthreads();
  {
    const int ttl = tid & 63, ebl = (tid>>6)*16;
    for (int i=0;i<16;i++)
      qvT[(size_t)(e0+ebl+i)*TT + t0+ttl] = tile[ttl][ebl+i];
  }
}

// ---------------- attention pass 1: softmax stats (m, 1/l) ----------------
// grid (TT/64, HH); 4 waves; each wave owns 16 query rows.
__global__ __launch_bounds__(256) void k_attn1_stats(
    const unsigned short* __restrict__ qh, const unsigned short* __restrict__ ql,
    const unsigned short* __restrict__ kh, const unsigned short* __restrict__ kl,
    float* __restrict__ m1, float* __restrict__ il1)
{
  const int h = blockIdx.y, tblk = blockIdx.x;
  const int w = threadIdx.x>>6, lane = threadIdx.x&63;
  const int row_base = tblk*64 + w*16;
  const int lrow = (lane>>4)*4;
  bf16x8 qhf[4], qlf[4];
  {
    const size_t qo = (size_t)(row_base + (lane&15))*EE + h*DD + (lane>>4)*8;
    #pragma unroll
    for (int kc=0;kc<4;kc++){
      qhf[kc] = *(const bf16x8*)(qh + qo + kc*32);
      qlf[kc] = *(const bf16x8*)(ql + qo + kc*32);
    }
  }
  float m_r[4], l_r[4];
  #pragma unroll
  for (int r=0;r<4;r++){ m_r[r] = -3.0e38f; l_r[r] = 0.f; }
  for (int st=0; st<=tblk; ++st){
    f32x4 S[4];
    #pragma unroll
    for (int n=0;n<4;n++){
      f32x4 a = {0.f,0.f,0.f,0.f};
      const size_t ko = (size_t)(st*64 + n*16 + (lane&15))*EE + h*DD + (lane>>4)*8;
      #pragma unroll
      for (int kc=0;kc<4;kc++){
        const bf16x8 khf = *(const bf16x8*)(kh + ko + kc*32);
        const bf16x8 klf = *(const bf16x8*)(kl + ko + kc*32);
        a = MFMA_BF16(qhf[kc], khf, a);
        a = MFMA_BF16(qlf[kc], khf, a);
        a = MFMA_BF16(qhf[kc], klf, a);
      }
      S[n] = a;
    }
    #pragma unroll
    for (int r=0;r<4;r++){
      const int row = row_base + lrow + r;
      float tmax = -3.0e38f;
      #pragma unroll
      for (int n=0;n<4;n++){
        const int col = st*64 + n*16 + (lane&15);
        tmax = fmaxf(tmax, (col<=row) ? S[n][r] : -3.0e38f);
      }
      tmax = fmaxf(tmax, __shfl_xor(tmax,1));
      tmax = fmaxf(tmax, __shfl_xor(tmax,2));
      tmax = fmaxf(tmax, __shfl_xor(tmax,4));
      tmax = fmaxf(tmax, __shfl_xor(tmax,8));
      const float nm = fmaxf(m_r[r], tmax);
      float rs = 0.f;
      #pragma unroll
      for (int n=0;n<4;n++){
        const int col = st*64 + n*16 + (lane&15);
        rs += (col<=row) ? __expf(S[n][r]-nm) : 0.f;
      }
      rs += __shfl_xor(rs,1); rs += __shfl_xor(rs,2);
      rs += __shfl_xor(rs,4); rs += __shfl_xor(rs,8);
      l_r[r] = l_r[r]*__expf(m_r[r]-nm) + rs;
      m_r[r] = nm;
    }
  }
  if ((lane&15)==0){
    #pragma unroll
    for (int r=0;r<4;r++){
      const int row = row_base + lrow + r;
      m1 [h*TT + row] = m_r[r];
      il1[h*TT + row] = 1.f / l_r[r];
    }
  }
}

// ---------------- attention pass 1b: accumulate per-key prob column sums ----------------
__global__ __launch_bounds__(256) void k_attn1_acc(
    const unsigned short* __restrict__ qh, const unsigned short* __restrict__ ql,
    const unsigned short* __restrict__ kh, const unsigned short* __restrict__ kl,
    const float* __restrict__ m1, const float* __restrict__ il1,
    float* __restrict__ partial)
{
  __shared__ float accw[4][TT];
  const int h = blockIdx.y, tblk = blockIdx.x;
  const int w = threadIdx.x>>6, lane = threadIdx.x&63;
  const int row_base = tblk*64 + w*16;
  const int lrow = (lane>>4)*4;
  for (int i=threadIdx.x; i<4*TT; i+=256) (&accw[0][0])[i] = 0.f;
  __syncthreads();
  bf16x8 qhf[4], qlf[4];
  {
    const size_t qo = (size_t)(row_base + (lane&15))*EE + h*DD + (lane>>4)*8;
    #pragma unroll
    for (int kc=0;kc<4;kc++){
      qhf[kc] = *(const bf16x8*)(qh + qo + kc*32);
      qlf[kc] = *(const bf16x8*)(ql + qo + kc*32);
    }
  }
  float m_r[4], il_r[4];
  #pragma unroll
  for (int r=0;r<4;r++){
    const int row = row_base + lrow + r;
    m_r[r] = m1[h*TT + row]; il_r[r] = il1[h*TT + row];
  }
  for (int st=0; st<=tblk; ++st){
    f32x4 S[4];
    #pragma unroll
    for (int n=0;n<4;n++){
      f32x4 a = {0.f,0.f,0.f,0.f};
      const size_t ko = (size_t)(st*64 + n*16 + (lane&15))*EE + h*DD + (lane>>4)*8;
      #pragma unroll
      for (int kc=0;kc<4;kc++){
        const bf16x8 khf = *(const bf16x8*)(kh + ko + kc*32);
        const bf16x8 klf = *(const bf16x8*)(kl + ko + kc*32);
        a = MFMA_BF16(qhf[kc], khf, a);
        a = MFMA_BF16(qlf[kc], khf, a);
        a = MFMA_BF16(qhf[kc], klf, a);
      }
      S[n] = a;
    }
    #pragma unroll
    for (int n=0;n<4;n++){
      const int col = st*64 + n*16 + (lane&15);
      float cs = 0.f;
      #pragma unroll
      for (int r=0;r<4;r++){
        const int row = row_base + lrow + r;
        cs += (col<=row) ? __expf(S[n][r]-m_r[r])*il_r[r] : 0.f;
      }
      cs += __shfl_xor(cs,16);
      cs += __shfl_xor(cs,32);
      if (lane < 16) accw[w][st*64 + n*16 + lane] = cs;  // unique col per (st,n,lane)
    }
  }
  __syncthreads();
  const int bid = blockIdx.y*gridDim.x + blockIdx.x;
  for (int i=threadIdx.x; i<TT; i+=256)
    partial[(size_t)bid*TT + i] = accw[0][i]+accw[1][i]+accw[2][i]+accw[3][i];
}

// ---------------- reduce + per-quarter top-51 (deterministic) ----------------
__global__ __launch_bounds__(512) void k_topk(
    const float* __restrict__ partial, int* __restrict__ imp)
{
  __shared__ float vals[512];
  __shared__ int   idxs[512];
  const int tid = threadIdx.x;
  const int s = blockIdx.x*512 + tid;
  float a = 0.f;
  for (int b=0;b<512;b++) a += partial[(size_t)b*TT + s];
  a = a / (float)(TT - s) / 16.f;      // / row_vector / (B*H)
  float myv = a;
  for (int it=0; it<51; ++it){
    vals[tid] = myv; idxs[tid] = s;
    __syncthreads();
    for (int off=256; off>0; off>>=1){
      if (tid < off){
        const float ov = vals[tid+off]; const int oi = idxs[tid+off];
        if (ov > vals[tid] || (ov == vals[tid] && oi < idxs[tid])){ vals[tid]=ov; idxs[tid]=oi; }
      }
      __syncthreads();
    }
    const int widx = idxs[0];
    __syncthreads();
    if (s == widx){ myv = -3.0e38f; imp[s] = 1; }
  }
}

// ---------------- attention pass 2: flash with quantized K/V ----------------
__global__ __launch_bounds__(256) void k_attn2(
    const unsigned short* __restrict__ qh, const unsigned short* __restrict__ ql,
    const unsigned short* __restrict__ qkm, const float* __restrict__ sk,
    const unsigned short* __restrict__ qvT, const float* __restrict__ sv,
    float* __restrict__ ctx)
{
  __shared__ unsigned short Ph[4][16*64];
  __shared__ unsigned short Pl[4][16*64];
  const int h = blockIdx.y, tblk = blockIdx.x;
  const int w = threadIdx.x>>6, lane = threadIdx.x&63;
  const int row_base = tblk*64 + w*16;
  const int lrow = (lane>>4)*4;
  bf16x8 qhf[4], qlf[4];
  {
    const size_t qo = (size_t)(row_base + (lane&15))*EE + h*DD + (lane>>4)*8;
    #pragma unroll
    for (int kc=0;kc<4;kc++){
      qhf[kc] = *(const bf16x8*)(qh + qo + kc*32);
      qlf[kc] = *(const bf16x8*)(ql + qo + kc*32);
    }
  }
  float m_r[4], l_r[4];
  f32x4 oa[8];
  const f32x4 FZ = {0.f,0.f,0.f,0.f};
  #pragma unroll
  for (int r=0;r<4;r++){ m_r[r] = -3.0e38f; l_r[r] = 0.f; }
  #pragma unroll
  for (int d8=0; d8<8; ++d8) oa[d8] = FZ;

  for (int st=0; st<=tblk; ++st){
    f32x4 S[4];
    #pragma unroll
    for (int n=0;n<4;n++){
      f32x4 a = {0.f,0.f,0.f,0.f};
      const size_t ko = (size_t)(st*64 + n*16 + (lane&15))*EE + h*DD + (lane>>4)*8;
      #pragma unroll
      for (int kc=0;kc<4;kc++){
        const bf16x8 kf = *(const bf16x8*)(qkm + ko + kc*32);
        a = MFMA_BF16(qhf[kc], kf, a);
        a = MFMA_BF16(qlf[kc], kf, a);
      }
      S[n] = a * sk[st*64 + n*16 + (lane&15)];
    }
    float p[4][4]; float scale[4];
    #pragma unroll
    for (int r=0;r<4;r++){
      const int row = row_base + lrow + r;
      float tmax = -3.0e38f;
      #pragma unroll
      for (int n=0;n<4;n++){
        const int col = st*64 + n*16 + (lane&15);
        tmax = fmaxf(tmax, (col<=row) ? S[n][r] : -3.0e38f);
      }
      tmax = fmaxf(tmax, __shfl_xor(tmax,1));
      tmax = fmaxf(tmax, __shfl_xor(tmax,2));
      tmax = fmaxf(tmax, __shfl_xor(tmax,4));
      tmax = fmaxf(tmax, __shfl_xor(tmax,8));
      const float nm = fmaxf(m_r[r], tmax);
      scale[r] = __expf(m_r[r]-nm);
      float rs = 0.f;
      #pragma unroll
      for (int n=0;n<4;n++){
        const int col = st*64 + n*16 + (lane&15);
        const float pv = (col<=row) ? __expf(S[n][r]-nm) : 0.f;
        p[n][r] = pv; rs += pv;
      }
      rs += __shfl_xor(rs,1); rs += __shfl_xor(rs,2);
      rs += __shfl_xor(rs,4); rs += __shfl_xor(rs,8);
      l_r[r] = l_r[r]*scale[r] + rs;
      m_r[r] = nm;
    }
    #pragma unroll
    for (int d8=0; d8<8; ++d8){
      #pragma unroll
      for (int r=0;r<4;r++) oa[d8][r] *= scale[r];
    }
    #pragma unroll
    for (int n=0;n<4;n++){
      #pragma unroll
      for (int r=0;r<4;r++){
        const unsigned short phv = f2bf(p[n][r]);
        Ph[w][(lrow+r)*64 + n*16 + (lane&15)] = phv;
        Pl[w][(lrow+r)*64 + n*16 + (lane&15)] = f2bf(p[n][r] - bf2f(phv));
      }
    }
    __syncthreads();
    bf16x8 pah[2], pal[2];
    #pragma unroll
    for (int kc=0;kc<2;kc++){
      pah[kc] = *(const bf16x8*)&Ph[w][(lane&15)*64 + kc*32 + (lane>>4)*8];
      pal[kc] = *(const bf16x8*)&Pl[w][(lane&15)*64 + kc*32 + (lane>>4)*8];
    }
    #pragma unroll
    for (int d8=0; d8<8; ++d8){
      const size_t vo = (size_t)(h*DD + d8*16 + (lane&15))*TT + st*64 + (lane>>4)*8;
      const bf16x8 v0 = *(const bf16x8*)(qvT + vo);
      const bf16x8 v1 = *(const bf16x8*)(qvT + vo + 32);
      oa[d8] = MFMA_BF16(pah[0], v0, oa[d8]);
      oa[d8] = MFMA_BF16(pal[0], v0, oa[d8]);
      oa[d8] = MFMA_BF16(pah[1], v1, oa[d8]);
      oa[d8] = MFMA_BF16(pal[1], v1, oa[d8]);
    }
    __syncthreads();
  }
  #pragma unroll
  for (int d8=0; d8<8; ++d8){
    const float sve = sv[h*DD + d8*16 + (lane&15)];
    #pragma unroll
    for (int r=0;r<4;r++){
      const int row = row_base + lrow + r;
      ctx[(size_t)row*EE + h*DD + d8*16 + (lane&15)] = oa[d8][r]*sve/l_r[r];
    }
  }
}

// ---------------- host launch ----------------
extern "C" void kernel_launch(void* const* d_in, const int* in_sizes, int n_in,
                              void* d_out, int out_size, void* d_ws, size_t ws_size,
                              hipStream_t stream)
{
  (void)in_sizes; (void)n_in; (void)out_size; (void)ws_size;
  const float* hs  = (const float*)d_in[0];
  const float* q_w = (const float*)d_in[2];
  const float* q_b = (const float*)d_in[3];
  const float* k_w = (const float*)d_in[4];
  const float* k_b = (const float*)d_in[5];
  const float* v_w = (const float*)d_in[6];
  const float* v_b = (const float*)d_in[7];
  const float* o_w = (const float*)d_in[8];
  const float* o_b = (const float*)d_in[9];

  char* p = (char*)d_ws;
  auto alloc = [&](size_t n)->void* {
    void* r = (void*)p; p += (n + 255) & ~(size_t)255; return r;
  };
  const size_t SZ_BF = (size_t)TT*EE*2;
  const size_t SZ_F  = (size_t)TT*EE*4;
  unsigned short* qx   = (unsigned short*)alloc(SZ_BF);
  float*          sx   = (float*)alloc(TT*4);
  unsigned short* qw   = (unsigned short*)alloc(SZ_BF);   // reused for all 4 weights
  float*          sw   = (float*)alloc(EE*4);
  unsigned short* q_hi = (unsigned short*)alloc(SZ_BF);
  unsigned short* q_lo = (unsigned short*)alloc(SZ_BF);
  float*          kbuf = (float*)alloc(SZ_F);
  unsigned short* k_hi = (unsigned short*)alloc(SZ_BF);
  unsigned short* k_lo = (unsigned short*)alloc(SZ_BF);
  float*          vbuf = (float*)alloc(SZ_F);
  float*          m1   = (float*)alloc((size_t)HH*TT*4);
  float*          il1  = (float*)alloc((size_t)HH*TT*4);
  float*          partial = (float*)alloc((size_t)512*TT*4);
  int*            imp  = (int*)alloc(TT*4);
  float*          skv  = (float*)alloc(TT*4);
  unsigned*       sv_bits = (unsigned*)alloc(EE*4);
  float*          sv   = (float*)alloc(EE*4);
  unsigned short* qvT  = (unsigned short*)alloc(SZ_BF);
  float*          sctx = (float*)alloc(TT*4);
  // aliases (lifetimes are disjoint, stream-ordered):
  unsigned short* qkm  = k_hi;   // k_hi/k_lo dead after pass-1b
  float*          ctx  = kbuf;   // kbuf dead after k_quant_kmixed
  unsigned short* qctx = qx;     // qx dead after V GEMM

  dim3 b256(256);
  dim3 gg(EE/128, TT/128);
  dim3 ga(TT/64, HH);

  // 1. quantize hidden states
  k_rowquant<<<TT, b256, 0, stream>>>(hs, qx, sx, 127.f);
  // 2. Q/K/V projections (exact int8-in-bf16 GEMMs)
  k_rowquant<<<EE, b256, 0, stream>>>(q_w, qw, sw, 127.f);
  k_gemm<<<gg, b256, 0, stream>>>(qx, sx, qw, sw, q_b, F_SCALING, nullptr, q_hi, q_lo);
  k_rowquant<<<EE, b256, 0, stream>>>(k_w, qw, sw, 127.f);
  k_gemm<<<gg, b256, 0, stream>>>(qx, sx, qw, sw, k_b, 1.f, kbuf, k_hi, k_lo);
  k_rowquant<<<EE, b256, 0, stream>>>(v_w, qw, sw, 127.f);
  k_gemm<<<gg, b256, 0, stream>>>(qx, sx, qw, sw, v_b, 1.f, vbuf, nullptr, nullptr);
  // 3. v = quant_absmax_last(vraw) (in place)
  k_quantdq_row<<<TT, b256, 0, stream>>>(vbuf, vbuf);
  // 4. V per-column quant (transposed int store)
  k_init<<<8, b256, 0, stream>>>(sv_bits, imp);
  k_colmax<<<dim3(EE/256, TT/256), b256, 0, stream>>>(vbuf, sv_bits);
  k_vq_transpose<<<dim3(TT/64, EE/64), b256, 0, stream>>>(vbuf, sv_bits, sv, qvT);
  // 5. attention pass 1 (stats, then column-sum accumulation)
  k_attn1_stats<<<ga, b256, 0, stream>>>(q_hi, q_lo, k_hi, k_lo, m1, il1);
  k_attn1_acc<<<ga, b256, 0, stream>>>(q_hi, q_lo, k_hi, k_lo, m1, il1, partial);
  // 6. top-k per quarter
  k_topk<<<4, dim3(512), 0, stream>>>(partial, imp);
  // 7. mixed K quantization
  k_quant_kmixed<<<TT, b256, 0, stream>>>(kbuf, imp, qkm, skv);
  // 8. attention pass 2 (flash)
  k_attn2<<<ga, b256, 0, stream>>>(q_hi, q_lo, qkm, skv, qvT, sv, ctx);
  // 9. output projection
  k_rowquant<<<TT, b256, 0, stream>>>(ctx, qctx, sctx, 127.f);
  k_rowquant<<<EE, b256, 0, stream>>>(o_w, qw, sw, 127.f);
  k_gemm<<<gg, b256, 0, stream>>>(qctx, sctx, qw, sw, o_b, 1.f, (float*)d_out, nullptr, nullptr);
}

// Round 2
// 706.384 us; speedup vs baseline: 1.5451x; 1.5451x over previous
//
#include <hip/hip_runtime.h>
#include <stdint.h>

#define TT 2048
#define EE 2048
#define HH 16
#define DD 128

static constexpr float F_EPS = 1e-5f;
static constexpr float F_SCALING = (float)0.08838834764831845; // 128^-0.5

using f32x4  = __attribute__((ext_vector_type(4))) float;
using bf16x8 = __attribute__((ext_vector_type(8))) short;
using u16x8  = __attribute__((ext_vector_type(8))) unsigned short;

#define MFMA_BF16(a,b,c) __builtin_amdgcn_mfma_f32_16x16x32_bf16((a),(b),(c),0,0,0)

#define GLD16(gp, lp) __builtin_amdgcn_global_load_lds( \
    (__attribute__((address_space(1))) void*)(unsigned long long)(gp), \
    (__attribute__((address_space(3))) void*)(lp), 16, 0, 0)

__device__ __forceinline__ unsigned short f2bf(float x){
  unsigned u = __float_as_uint(x);
  u = (u + 0x7FFFu + ((u >> 16) & 1u)) >> 16;
  return (unsigned short)u;
}
__device__ __forceinline__ float bf2f(unsigned short h){
  return __uint_as_float(((unsigned)h) << 16);
}

// chunk enumeration: per head, 80 blocks cover the causal triangle with <=8 tiles each
// qt 0..7: 1 chunk; 8..15: 2; 16..23: 3; 24..31: 4
__device__ __forceinline__ void cid_map(int cid, int& qt, int& ch, int& nc){
  if (cid < 8)       { qt = cid;                ch = 0;            nc = 1; }
  else if (cid < 24) { qt = 8  + ((cid-8)>>1);  ch = (cid-8)&1;    nc = 2; }
  else if (cid < 48) { qt = 16 + (cid-24)/3;    ch = (cid-24)%3;   nc = 3; }
  else               { qt = 24 + ((cid-48)>>2); ch = (cid-48)&3;   nc = 4; }
}
__device__ __forceinline__ int aoff(int qt){  // slot offset among qt>=8 (attn2 partials)
  return (qt<16) ? 2*(qt-8) : ((qt<24) ? 16+3*(qt-16) : 40+4*(qt-24));
}

// ---- LDS staging with XOR swizzle (byte ^= (row&7)<<4), swizzle applied on the
// GLOBAL source address (global_load_lds writes LDS linearly), and again on reads.
__device__ __forceinline__ void stage_k64x128(const unsigned short* gbase, unsigned short* lds, int tid){
  const char* gb = (const char*)gbase;
  char* lb = (char*)lds;
  #pragma unroll
  for (int i=0;i<4;i++){
    const int idx = i*256 + tid;            // 16B chunk id; 16 chunks per 64 rows? 16/row
    const int r = idx >> 4, c = idx & 15;
    GLD16(gb + (size_t)r*(EE*2) + (unsigned)((c*16) ^ ((r&7)<<4)), lb + idx*16);
  }
}
__device__ __forceinline__ void stage_v128x64(const unsigned short* gbase, unsigned short* lds, int tid){
  const char* gb = (const char*)gbase;
  char* lb = (char*)lds;
  #pragma unroll
  for (int i=0;i<4;i++){
    const int idx = i*256 + tid;            // 8 chunks per 128-dim row
    const int r = idx >> 3, c = idx & 7;
    GLD16(gb + (size_t)r*(TT*2) + (unsigned)((c*16) ^ ((r&7)<<4)), lb + idx*16);
  }
}
__device__ __forceinline__ bf16x8 frag_k(const unsigned short* lds, int kr, int dbyte){
  return *(const bf16x8*)((const char*)lds + kr*256 + (dbyte ^ ((kr&7)<<4)));
}
__device__ __forceinline__ bf16x8 frag_v(const unsigned short* lds, int dr, int kbyte){
  return *(const bf16x8*)((const char*)lds + dr*128 + (kbyte ^ ((dr&7)<<4)));
}

// ---------------- row-wise quantization kernels ----------------
__global__ __launch_bounds__(256) void k_rowquant(
    const float* __restrict__ in, unsigned short* __restrict__ outq,
    float* __restrict__ outs, float qmax)
{
  const int row = blockIdx.x;
  const int tid = threadIdx.x;
  const float* r = in + (size_t)row * EE;
  float x[8];
  {
    const f32x4 a = *(const f32x4*)(r + tid*8);
    const f32x4 b = *(const f32x4*)(r + tid*8 + 4);
    x[0]=a[0]; x[1]=a[1]; x[2]=a[2]; x[3]=a[3];
    x[4]=b[0]; x[5]=b[1]; x[6]=b[2]; x[7]=b[3];
  }
  float am = 0.f;
  #pragma unroll
  for (int j=0;j<8;j++) am = fmaxf(am, fabsf(x[j]));
  #pragma unroll
  for (int o=1;o<64;o<<=1) am = fmaxf(am, __shfl_xor(am, o));
  __shared__ float red[4];
  if ((tid&63)==0) red[tid>>6] = am;
  __syncthreads();
  am = fmaxf(fmaxf(red[0],red[1]), fmaxf(red[2],red[3]));
  const float s = fmaxf(am, F_EPS) / qmax;
  if (tid==0) outs[row] = s;
  u16x8 qv;
  #pragma unroll
  for (int j=0;j<8;j++) qv[j] = f2bf(rintf(x[j]/s));
  *(u16x8*)(outq + (size_t)row*EE + tid*8) = qv;
}

__global__ __launch_bounds__(256) void k_quantdq_row(
    const float* __restrict__ in, float* __restrict__ out)
{
  const int row = blockIdx.x;
  const int tid = threadIdx.x;
  const float* r = in + (size_t)row * EE;
  float x[8];
  {
    const f32x4 a = *(const f32x4*)(r + tid*8);
    const f32x4 b = *(const f32x4*)(r + tid*8 + 4);
    x[0]=a[0]; x[1]=a[1]; x[2]=a[2]; x[3]=a[3];
    x[4]=b[0]; x[5]=b[1]; x[6]=b[2]; x[7]=b[3];
  }
  float am = 0.f;
  #pragma unroll
  for (int j=0;j<8;j++) am = fmaxf(am, fabsf(x[j]));
  #pragma unroll
  for (int o=1;o<64;o<<=1) am = fmaxf(am, __shfl_xor(am, o));
  __shared__ float red[4];
  if ((tid&63)==0) red[tid>>6] = am;
  __syncthreads();
  am = fmaxf(fmaxf(red[0],red[1]), fmaxf(red[2],red[3]));
  const float s = fmaxf(am, F_EPS) / 127.f;
  f32x4 o0, o1;
  o0[0]=rintf(x[0]/s)*s; o0[1]=rintf(x[1]/s)*s; o0[2]=rintf(x[2]/s)*s; o0[3]=rintf(x[3]/s)*s;
  o1[0]=rintf(x[4]/s)*s; o1[1]=rintf(x[5]/s)*s; o1[2]=rintf(x[6]/s)*s; o1[3]=rintf(x[7]/s)*s;
  *(f32x4*)(out + (size_t)row*EE + tid*8)     = o0;
  *(f32x4*)(out + (size_t)row*EE + tid*8 + 4) = o1;
}

__global__ __launch_bounds__(256) void k_quant_kmixed(
    const float* __restrict__ kin, const int* __restrict__ imp,
    unsigned short* __restrict__ qkm, float* __restrict__ sk)
{
  const int row = blockIdx.x;
  const int tid = threadIdx.x;
  const float* r = kin + (size_t)row * EE;
  float x[8];
  {
    const f32x4 a = *(const f32x4*)(r + tid*8);
    const f32x4 b = *(const f32x4*)(r + tid*8 + 4);
    x[0]=a[0]; x[1]=a[1]; x[2]=a[2]; x[3]=a[3];
    x[4]=b[0]; x[5]=b[1]; x[6]=b[2]; x[7]=b[3];
  }
  float am = 0.f;
  #pragma unroll
  for (int j=0;j<8;j++) am = fmaxf(am, fabsf(x[j]));
  #pragma unroll
  for (int o=1;o<64;o<<=1) am = fmaxf(am, __shfl_xor(am, o));
  __shared__ float red[4];
  if ((tid&63)==0) red[tid>>6] = am;
  __syncthreads();
  am = fmaxf(fmaxf(red[0],red[1]), fmaxf(red[2],red[3]));
  float s;
  if (imp[row]) s = fmaxf(am / 127.f, F_EPS);
  else          s = fmaxf(am, F_EPS) / 7.f;
  if (tid==0) sk[row] = s;
  u16x8 qv;
  #pragma unroll
  for (int j=0;j<8;j++) qv[j] = f2bf(rintf(x[j]/s));
  *(u16x8*)(qkm + (size_t)row*EE + tid*8) = qv;
}

// ---------------- GEMM (unchanged, 128x128 tile, BK=64) ----------------
__global__ __launch_bounds__(256) void k_gemm(
    const unsigned short* __restrict__ Aq, const float* __restrict__ sa,
    const unsigned short* __restrict__ Bq, const float* __restrict__ sb,
    const float* __restrict__ bias, float post_scale,
    float* __restrict__ Cout, unsigned short* __restrict__ Hout,
    unsigned short* __restrict__ Lout)
{
  __shared__ unsigned short lA[128*64];
  __shared__ unsigned short lB[128*64];
  const int tid = threadIdx.x;
  const int bm = blockIdx.y, bn = blockIdx.x;
  const int lane = tid & 63, w = tid >> 6;
  const int wr = w >> 1, wc = w & 1;
  const int rA = tid >> 3;
  const int cA = (tid & 7) * 8;
  f32x4 acc[4][4];
  const f32x4 FZ = {0.f,0.f,0.f,0.f};
  #pragma unroll
  for (int i=0;i<4;i++)
    #pragma unroll
    for (int j=0;j<4;j++) acc[i][j] = FZ;

  const unsigned short* gA0 = Aq + (size_t)(bm*128 + rA)*EE + cA;
  const unsigned short* gB0 = Bq + (size_t)(bn*128 + rA)*EE + cA;
  unsigned short* lA0 = lA + tid*8;
  unsigned short* lB0 = lB + tid*8;

  for (int k0 = 0; k0 < EE; k0 += 64) {
    #pragma unroll
    for (int i=0;i<4;i++) GLD16(gA0 + (size_t)i*32*EE + k0, lA0 + i*2048);
    #pragma unroll
    for (int i=0;i<4;i++) GLD16(gB0 + (size_t)i*32*EE + k0, lB0 + i*2048);
    __syncthreads();
    #pragma unroll
    for (int kk=0;kk<2;kk++){
      bf16x8 af[4], bfr[4];
      #pragma unroll
      for (int mi=0;mi<4;mi++)
        af[mi] = *(const bf16x8*)(lA + (wr*64 + mi*16 + (lane&15))*64 + kk*32 + (lane>>4)*8);
      #pragma unroll
      for (int ni=0;ni<4;ni++)
        bfr[ni] = *(const bf16x8*)(lB + (wc*64 + ni*16 + (lane&15))*64 + kk*32 + (lane>>4)*8);
      #pragma unroll
      for (int mi=0;mi<4;mi++)
        #pragma unroll
        for (int ni=0;ni<4;ni++)
          acc[mi][ni] = MFMA_BF16(af[mi], bfr[ni], acc[mi][ni]);
    }
    __syncthreads();
  }
  const int row0 = bm*128 + wr*64;
  const int col0 = bn*128 + wc*64;
  #pragma unroll
  for (int mi=0;mi<4;mi++){
    #pragma unroll
    for (int r=0;r<4;r++){
      const int row = row0 + mi*16 + (lane>>4)*4 + r;
      const float sav = sa[row];
      #pragma unroll
      for (int ni=0;ni<4;ni++){
        const int col = col0 + ni*16 + (lane&15);
        const float v = (acc[mi][ni][r]*sav*sb[col] + bias[col]) * post_scale;
        if (Cout) Cout[(size_t)row*EE + col] = v;
        if (Hout){
          const unsigned short hh = f2bf(v);
          Hout[(size_t)row*EE + col] = hh;
          Lout[(size_t)row*EE + col] = f2bf(v - bf2f(hh));
        }
      }
    }
  }
}

// ---------------- V per-column quant ----------------
__global__ void k_init(unsigned* __restrict__ sv_bits, int* __restrict__ imp)
{
  const int i = blockIdx.x*256 + threadIdx.x;
  if (i < EE) sv_bits[i] = 0u;
  if (i < TT) imp[i] = 0;
}

__global__ __launch_bounds__(256) void k_colmax(
    const float* __restrict__ v, unsigned* __restrict__ sv_bits)
{
  const int e = blockIdx.x*256 + threadIdx.x;
  const int t0 = blockIdx.y*256;
  float am = 0.f;
  for (int t=t0; t<t0+256; ++t) am = fmaxf(am, fabsf(v[(size_t)t*EE + e]));
  atomicMax(sv_bits + e, __float_as_uint(am));
}

__global__ __launch_bounds__(256) void k_vq_transpose(
    const float* __restrict__ v, const unsigned* __restrict__ sv_bits,
    float* __restrict__ sv, unsigned short* __restrict__ qvT)
{
  __shared__ unsigned short tile[64][66];
  const int t0 = blockIdx.x*64, e0 = blockIdx.y*64;
  const int tid = threadIdx.x;
  {
    const int ee = tid & 63, tb = (tid>>6)*16;
    const float sve = fmaxf(__uint_as_float(sv_bits[e0+ee]), F_EPS) / 127.f;
    for (int i=0;i<16;i++)
      tile[tb+i][ee] = f2bf(rintf(v[(size_t)(t0+tb+i)*EE + e0+ee] / sve));
  }
  if (blockIdx.x==0 && tid<64)
    sv[e0+tid] = fmaxf(__uint_as_float(sv_bits[e0+tid]), F_EPS) / 127.f;
  __syncthreads();
  {
    const int ttl = tid & 63, ebl = (tid>>6)*16;
    for (int i=0;i<16;i++)
      qvT[(size_t)(e0+ebl+i)*TT + t0+ttl] = tile[ttl][ebl+i];
  }
}

// ---------------- attention pass 1: chunked softmax stats ----------------
__global__ __launch_bounds__(256) void k_attn1_stats(
    const unsigned short* __restrict__ qh, const unsigned short* __restrict__ ql,
    const unsigned short* __restrict__ kh, const unsigned short* __restrict__ kl,
    float* __restrict__ mp, float* __restrict__ lp)
{
  __shared__ unsigned short lKh[64*128];
  __shared__ unsigned short lKl[64*128];
  const int h = blockIdx.y, cid = blockIdx.x;
  int qt, ch, nc; cid_map(cid, qt, ch, nc);
  const int per = (qt + nc)/nc;
  const int s0 = ch*per, s1 = min(s0+per-1, qt);
  const int tid = threadIdx.x, w = tid>>6, lane = tid&63;
  const int row_base = qt*64 + w*16, lrow = (lane>>4)*4;
  bf16x8 qhf[4], qlf[4];
  {
    const size_t qo = (size_t)(row_base + (lane&15))*EE + h*DD + (lane>>4)*8;
    #pragma unroll
    for (int kc=0;kc<4;kc++){
      qhf[kc] = *(const bf16x8*)(qh + qo + kc*32);
      qlf[kc] = *(const bf16x8*)(ql + qo + kc*32);
    }
  }
  float m_r[4], l_r[4];
  #pragma unroll
  for (int r=0;r<4;r++){ m_r[r] = -3.0e38f; l_r[r] = 0.f; }
  stage_k64x128(kh + (size_t)(s0*64)*EE + h*DD, lKh, tid);
  stage_k64x128(kl + (size_t)(s0*64)*EE + h*DD, lKl, tid);
  for (int st=s0; st<=s1; ++st){
    __syncthreads();                       // staged data ready (vmcnt drained)
    f32x4 S[4];
    #pragma unroll
    for (int n=0;n<4;n++){
      f32x4 a = {0.f,0.f,0.f,0.f};
      const int kr = n*16 + (lane&15);
      #pragma unroll
      for (int kc=0;kc<4;kc++){
        const int db = kc*64 + (lane>>4)*16;
        const bf16x8 khf = frag_k(lKh, kr, db);
        const bf16x8 klf = frag_k(lKl, kr, db);
        a = MFMA_BF16(qhf[kc], khf, a);
        a = MFMA_BF16(qlf[kc], khf, a);
        a = MFMA_BF16(qhf[kc], klf, a);
      }
      S[n] = a;
    }
    __syncthreads();                       // all waves done reading
    if (st < s1){                          // prefetch next tile under the softmax VALU
      stage_k64x128(kh + (size_t)((st+1)*64)*EE + h*DD, lKh, tid);
      stage_k64x128(kl + (size_t)((st+1)*64)*EE + h*DD, lKl, tid);
    }
    #pragma unroll
    for (int r=0;r<4;r++){
      const int row = row_base + lrow + r;
      float tmax = -3.0e38f;
      #pragma unroll
      for (int n=0;n<4;n++){
        const int col = st*64 + n*16 + (lane&15);
        tmax = fmaxf(tmax, (col<=row) ? S[n][r] : -3.0e38f);
      }
      tmax = fmaxf(tmax, __shfl_xor(tmax,1));
      tmax = fmaxf(tmax, __shfl_xor(tmax,2));
      tmax = fmaxf(tmax, __shfl_xor(tmax,4));
      tmax = fmaxf(tmax, __shfl_xor(tmax,8));
      const float nm = fmaxf(m_r[r], tmax);
      float rs = 0.f;
      #pragma unroll
      for (int n=0;n<4;n++){
        const int col = st*64 + n*16 + (lane&15);
        rs += (col<=row) ? __expf(S[n][r]-nm) : 0.f;
      }
      rs += __shfl_xor(rs,1); rs += __shfl_xor(rs,2);
      rs += __shfl_xor(rs,4); rs += __shfl_xor(rs,8);
      l_r[r] = l_r[r]*__expf(m_r[r]-nm) + rs;
      m_r[r] = nm;
    }
  }
  if ((lane&15)==0){
    const int slot = (h*80 + cid)*64;
    #pragma unroll
    for (int r=0;r<4;r++){
      mp[slot + w*16 + lrow + r] = m_r[r];
      lp[slot + w*16 + lrow + r] = l_r[r];
    }
  }
}

__global__ __launch_bounds__(64) void k_stats_combine(
    const float* __restrict__ mp, const float* __restrict__ lp,
    float* __restrict__ m1, float* __restrict__ il1)
{
  const int qt = blockIdx.x, h = blockIdx.y, r = threadIdx.x;
  const int nc  = (qt<8)?1:((qt<16)?2:((qt<24)?3:4));
  const int off = (qt<8)?qt:((qt<16)?8+2*(qt-8):((qt<24)?24+3*(qt-16):48+4*(qt-24)));
  const int base = (h*80 + off)*64 + r;
  float m = mp[base];
  for (int i=1;i<nc;i++) m = fmaxf(m, mp[base + i*64]);
  float l = 0.f;
  for (int i=0;i<nc;i++) l += lp[base + i*64]*__expf(mp[base + i*64]-m);
  m1[h*TT + qt*64 + r] = m;
  il1[h*TT + qt*64 + r] = 1.f/l;
}

// ---------------- attention pass 1b: chunked per-key prob column sums ----------------
__global__ __launch_bounds__(256) void k_attn1_acc(
    const unsigned short* __restrict__ qh, const unsigned short* __restrict__ ql,
    const unsigned short* __restrict__ kh, const unsigned short* __restrict__ kl,
    const float* __restrict__ m1, const float* __restrict__ il1,
    float* __restrict__ partial)
{
  __shared__ unsigned short lKh[64*128];
  __shared__ unsigned short lKl[64*128];
  __shared__ float accw[4][512];
  const int h = blockIdx.y, cid = blockIdx.x;
  int qt, ch, nc; cid_map(cid, qt, ch, nc);
  const int per = (qt + nc)/nc;
  const int s0 = ch*per, s1 = min(s0+per-1, qt);
  const int tid = threadIdx.x, w = tid>>6, lane = tid&63;
  const int row_base = qt*64 + w*16, lrow = (lane>>4)*4;
  bf16x8 qhf[4], qlf[4];
  {
    const size_t qo = (size_t)(row_base + (lane&15))*EE + h*DD + (lane>>4)*8;
    #pragma unroll
    for (int kc=0;kc<4;kc++){
      qhf[kc] = *(const bf16x8*)(qh + qo + kc*32);
      qlf[kc] = *(const bf16x8*)(ql + qo + kc*32);
    }
  }
  float m_r[4], il_r[4];
  #pragma unroll
  for (int r=0;r<4;r++){
    const int row = row_base + lrow + r;
    m_r[r] = m1[h*TT + row]; il_r[r] = il1[h*TT + row];
  }
  stage_k64x128(kh + (size_t)(s0*64)*EE + h*DD, lKh, tid);
  stage_k64x128(kl + (size_t)(s0*64)*EE + h*DD, lKl, tid);
  for (int st=s0; st<=s1; ++st){
    __syncthreads();
    f32x4 S[4];
    #pragma unroll
    for (int n=0;n<4;n++){
      f32x4 a = {0.f,0.f,0.f,0.f};
      const int kr = n*16 + (lane&15);
      #pragma unroll
      for (int kc=0;kc<4;kc++){
        const int db = kc*64 + (lane>>4)*16;
        const bf16x8 khf = frag_k(lKh, kr, db);
        const bf16x8 klf = frag_k(lKl, kr, db);
        a = MFMA_BF16(qhf[kc], khf, a);
        a = MFMA_BF16(qlf[kc], khf, a);
        a = MFMA_BF16(qhf[kc], klf, a);
      }
      S[n] = a;
    }
    __syncthreads();
    if (st < s1){
      stage_k64x128(kh + (size_t)((st+1)*64)*EE + h*DD, lKh, tid);
      stage_k64x128(kl + (size_t)((st+1)*64)*EE + h*DD, lKl, tid);
    }
    #pragma unroll
    for (int n=0;n<4;n++){
      const int col = st*64 + n*16 + (lane&15);
      float cs = 0.f;
      #pragma unroll
      for (int r=0;r<4;r++){
        const int row = row_base + lrow + r;
        cs += (col<=row) ? __expf(S[n][r]-m_r[r])*il_r[r] : 0.f;
      }
      cs += __shfl_xor(cs,16);
      cs += __shfl_xor(cs,32);
      if (lane < 16) accw[w][(st-s0)*64 + n*16 + lane] = cs;
    }
  }
  __syncthreads();
  const int ncols = (s1-s0+1)*64;
  float* dst = partial + (size_t)(h*32+qt)*TT + s0*64;
  for (int i=tid; i<ncols; i+=256)
    dst[i] = accw[0][i]+accw[1][i]+accw[2][i]+accw[3][i];
}

// ---------------- reduce + per-quarter top-51 (deterministic) ----------------
__global__ __launch_bounds__(512) void k_topk(
    const float* __restrict__ partial, int* __restrict__ imp)
{
  __shared__ float vals[512];
  __shared__ int   idxs[512];
  const int tid = threadIdx.x;
  const int s = blockIdx.x*512 + tid;
  float a = 0.f;
  const int tmin = s >> 6;
  for (int hh=0; hh<16; ++hh)
    for (int qt=tmin; qt<32; ++qt)
      a += partial[(size_t)(hh*32+qt)*TT + s];
  a = a / (float)(TT - s) / 16.f;
  float myv = a;
  for (int it=0; it<51; ++it){
    vals[tid] = myv; idxs[tid] = s;
    __syncthreads();
    for (int off=256; off>0; off>>=1){
      if (tid < off){
        const float ov = vals[tid+off]; const int oi = idxs[tid+off];
        if (ov > vals[tid] || (ov == vals[tid] && oi < idxs[tid])){ vals[tid]=ov; idxs[tid]=oi; }
      }
      __syncthreads();
    }
    const int widx = idxs[0];
    __syncthreads();
    if (s == widx){ myv = -3.0e38f; imp[s] = 1; }
  }
}

// ---------------- attention pass 2: chunked flash with quantized K/V ----------------
__global__ __launch_bounds__(256) void k_attn2(
    const unsigned short* __restrict__ qh, const unsigned short* __restrict__ ql,
    const unsigned short* __restrict__ qkm, const float* __restrict__ sk,
    const unsigned short* __restrict__ qvT, const float* __restrict__ sv,
    float* __restrict__ ctx, float* __restrict__ mp2, float* __restrict__ lp2,
    unsigned short* __restrict__ Opart)
{
  __shared__ unsigned short lK[64*128];
  __shared__ unsigned short lV[128*64];
  __shared__ unsigned short Ph[4][16*64];
  const int h = blockIdx.y, cid = blockIdx.x;
  int qt, ch, nc; cid_map(cid, qt, ch, nc);
  const int per = (qt + nc)/nc;
  const int s0 = ch*per, s1 = min(s0+per-1, qt);
  const int tid = threadIdx.x, w = tid>>6, lane = tid&63;
  const int row_base = qt*64 + w*16, lrow = (lane>>4)*4;
  bf16x8 qhf[4], qlf[4];
  {
    const size_t qo = (size_t)(row_base + (lane&15))*EE + h*DD + (lane>>4)*8;
    #pragma unroll
    for (int kc=0;kc<4;kc++){
      qhf[kc] = *(const bf16x8*)(qh + qo + kc*32);
      qlf[kc] = *(const bf16x8*)(ql + qo + kc*32);
    }
  }
  float m_r[4], l_r[4];
  f32x4 oa[8];
  const f32x4 FZ = {0.f,0.f,0.f,0.f};
  #pragma unroll
  for (int r=0;r<4;r++){ m_r[r] = -3.0e38f; l_r[r] = 0.f; }
  #pragma unroll
  for (int d8=0; d8<8; ++d8) oa[d8] = FZ;

  stage_k64x128(qkm + (size_t)(s0*64)*EE + h*DD, lK, tid);
  stage_v128x64(qvT + (size_t)(h*DD)*TT + s0*64, lV, tid);

  for (int st=s0; st<=s1; ++st){
    __syncthreads();                       // staged K/V ready
    f32x4 S[4];
    #pragma unroll
    for (int n=0;n<4;n++){
      f32x4 a = {0.f,0.f,0.f,0.f};
      const int kr = n*16 + (lane&15);
      #pragma unroll
      for (int kc=0;kc<4;kc++){
        const int db = kc*64 + (lane>>4)*16;
        const bf16x8 kf = frag_k(lK, kr, db);
        a = MFMA_BF16(qhf[kc], kf, a);
        a = MFMA_BF16(qlf[kc], kf, a);
      }
      S[n] = a * sk[st*64 + n*16 + (lane&15)];
    }
    float p[4][4]; float scale[4];
    #pragma unroll
    for (int r=0;r<4;r++){
      const int row = row_base + lrow + r;
      float tmax = -3.0e38f;
      #pragma unroll
      for (int n=0;n<4;n++){
        const int col = st*64 + n*16 + (lane&15);
        tmax = fmaxf(tmax, (col<=row) ? S[n][r] : -3.0e38f);
      }
      tmax = fmaxf(tmax, __shfl_xor(tmax,1));
      tmax = fmaxf(tmax, __shfl_xor(tmax,2));
      tmax = fmaxf(tmax, __shfl_xor(tmax,4));
      tmax = fmaxf(tmax, __shfl_xor(tmax,8));
      const float nm = fmaxf(m_r[r], tmax);
      scale[r] = __expf(m_r[r]-nm);
      float rs = 0.f;
      #pragma unroll
      for (int n=0;n<4;n++){
        const int col = st*64 + n*16 + (lane&15);
        const float pv = (col<=row) ? __expf(S[n][r]-nm) : 0.f;
        p[n][r] = pv; rs += pv;
      }
      rs += __shfl_xor(rs,1); rs += __shfl_xor(rs,2);
      rs += __shfl_xor(rs,4); rs += __shfl_xor(rs,8);
      l_r[r] = l_r[r]*scale[r] + rs;
      m_r[r] = nm;
    }
    #pragma unroll
    for (int d8=0; d8<8; ++d8){
      #pragma unroll
      for (int r=0;r<4;r++) oa[d8][r] *= scale[r];
    }
    // P -> LDS (bf16, XOR-swizzled rows)
    #pragma unroll
    for (int n=0;n<4;n++){
      #pragma unroll
      for (int r=0;r<4;r++){
        const int row = lrow + r;
        *(unsigned short*)((char*)&Ph[w][0] + row*128 +
            ((((n*16 + (lane&15))*2)) ^ ((row&7)<<4))) = f2bf(p[n][r]);
      }
    }
    __syncthreads();                       // (also covers cross-lane Ph visibility)
    bf16x8 pah[2];
    #pragma unroll
    for (int kc=0;kc<2;kc++){
      const int rr = lane&15;
      const int cb = kc*64 + (lane>>4)*16;
      pah[kc] = *(const bf16x8*)((const char*)&Ph[w][0] + rr*128 + (cb ^ ((rr&7)<<4)));
    }
    #pragma unroll
    for (int d8=0; d8<8; ++d8){
      const int dr = d8*16 + (lane&15);
      const int kb = (lane>>4)*16;
      const bf16x8 v0 = frag_v(lV, dr, kb);
      const bf16x8 v1 = frag_v(lV, dr, kb + 64);
      oa[d8] = MFMA_BF16(pah[0], v0, oa[d8]);
      oa[d8] = MFMA_BF16(pah[1], v1, oa[d8]);
    }
    __syncthreads();                       // all waves done with lK/lV/Ph
    if (st < s1){
      stage_k64x128(qkm + (size_t)((st+1)*64)*EE + h*DD, lK, tid);
      stage_v128x64(qvT + (size_t)(h*DD)*TT + (st+1)*64, lV, tid);
    }
  }
  if (nc == 1){
    #pragma unroll
    for (int d8=0; d8<8; ++d8){
      const float sve = sv[h*DD + d8*16 + (lane&15)];
      #pragma unroll
      for (int r=0;r<4;r++){
        const int row = row_base + lrow + r;
        ctx[(size_t)row*EE + h*DD + d8*16 + (lane&15)] = oa[d8][r]*sve/l_r[r];
      }
    }
  } else {
    const int slot = h*72 + aoff(qt) + ch;
    if ((lane&15)==0){
      #pragma unroll
      for (int r=0;r<4;r++){
        mp2[slot*64 + w*16 + lrow + r] = m_r[r];
        lp2[slot*64 + w*16 + lrow + r] = l_r[r];
      }
    }
    #pragma unroll
    for (int d8=0; d8<8; ++d8){
      #pragma unroll
      for (int r=0;r<4;r++)
        Opart[(size_t)slot*8192 + (w*16 + lrow + r)*128 + d8*16 + (lane&15)] = f2bf(oa[d8][r]);
    }
  }
}

__global__ __launch_bounds__(256) void k_attn2_combine(
    const float* __restrict__ mp2, const float* __restrict__ lp2,
    const unsigned short* __restrict__ Opart, const float* __restrict__ sv,
    float* __restrict__ ctx)
{
  __shared__ float wsc[4][64];
  __shared__ float lst[64];
  const int qt = 8 + blockIdx.x, h = blockIdx.y;
  const int nc = (qt + 8) >> 3;            // 2,3,4
  const int base = h*72 + aoff(qt);
  const int tid = threadIdx.x;
  if (tid < 64){
    float m = mp2[base*64 + tid];
    for (int i=1;i<nc;i++) m = fmaxf(m, mp2[(base+i)*64 + tid]);
    float l = 0.f;
    for (int i=0;i<nc;i++){
      const float wv = __expf(mp2[(base+i)*64 + tid] - m);
      wsc[i][tid] = wv;
      l += lp2[(base+i)*64 + tid]*wv;
    }
    lst[tid] = 1.f/l;
  }
  __syncthreads();
  #pragma unroll
  for (int e=0;e<32;e++){
    const int idx = e*256 + tid;
    const int row = idx>>7, d = idx&127;
    float a = 0.f;
    for (int i=0;i<nc;i++)
      a += bf2f(Opart[(size_t)(base+i)*8192 + idx]) * wsc[i][row];
    ctx[(size_t)(qt*64+row)*EE + h*DD + d] = a * sv[h*DD + d] * lst[row];
  }
}

// ---------------- host launch ----------------
extern "C" void kernel_launch(void* const* d_in, const int* in_sizes, int n_in,
                              void* d_out, int out_size, void* d_ws, size_t ws_size,
                              hipStream_t stream)
{
  (void)in_sizes; (void)n_in; (void)out_size; (void)ws_size;
  const float* hs  = (const float*)d_in[0];
  const float* q_w = (const float*)d_in[2];
  const float* q_b = (const float*)d_in[3];
  const float* k_w = (const float*)d_in[4];
  const float* k_b = (const float*)d_in[5];
  const float* v_w = (const float*)d_in[6];
  const float* v_b = (const float*)d_in[7];
  const float* o_w = (const float*)d_in[8];
  const float* o_b = (const float*)d_in[9];

  char* ws = (char*)d_ws;
  const size_t MB = 1ull<<20;
  // explicit layout (total ~92.3 MB; round-1 layout of ~92.4 MB is known to fit)
  unsigned short* qx   = (unsigned short*)(ws + 0*MB);    // 8 MB; reused: qctx at step 9
  unsigned short* qw   = (unsigned short*)(ws + 8*MB);    // 8 MB
  unsigned short* q_hi = (unsigned short*)(ws + 16*MB);   // 8 MB
  unsigned short* q_lo = (unsigned short*)(ws + 24*MB);   // 8 MB
  float*          kbuf = (float*)(ws + 32*MB);            // 16 MB; reused: ctx
  unsigned short* k_hi = (unsigned short*)(ws + 48*MB);   // 8 MB; reused: qkm
  unsigned short* k_lo = (unsigned short*)(ws + 56*MB);   // 8 MB
  float*          vbuf = (float*)(ws + 64*MB);            // 16 MB; dead after V quant
  float*          partial = (float*)(ws + 80*MB);         // 4 MB; dead after topk
  unsigned short* qvT  = (unsigned short*)(ws + 84*MB);   // 8 MB
  char*           sm   = ws + 92*MB;                      // smalls (~0.32 MB)
  float*    sx   = (float*)(sm + 0);
  float*    sw   = (float*)(sm + 16*1024);
  float*    m1   = (float*)(sm + 32*1024);
  float*    il1  = (float*)(sm + 168*1024);
  int*      imp  = (int*)(sm + 304*1024);
  float*    skv  = (float*)(sm + 316*1024);
  unsigned* sv_bits = (unsigned*)(sm + 328*1024);
  float*    sv   = (float*)(sm + 340*1024);
  float*    sctx = (float*)(sm + 352*1024);
  // overlays (disjoint lifetimes, stream-ordered):
  float* mp  = (float*)qx;                  // stats partials (655 KB) in dead qx
  float* lp  = mp + 80*16*64;
  float* mp2 = (float*)vbuf;                // attn2 m/l partials (590 KB) in dead vbuf
  float* lp2 = mp2 + 1152*64;
  unsigned short* Opart = (unsigned short*)(ws + 64*MB + 1*MB); // 18.9 MB in dead vbuf+partial
  unsigned short* qkm  = k_hi;
  float*          ctx  = kbuf;
  unsigned short* qctx = qx;

  dim3 b256(256);
  dim3 gg(EE/128, TT/128);
  dim3 ga(80, HH);

  // 1. quantize hidden states
  k_rowquant<<<TT, b256, 0, stream>>>(hs, qx, sx, 127.f);
  // 2. Q/K/V projections
  k_rowquant<<<EE, b256, 0, stream>>>(q_w, qw, sw, 127.f);
  k_gemm<<<gg, b256, 0, stream>>>(qx, sx, qw, sw, q_b, F_SCALING, nullptr, q_hi, q_lo);
  k_rowquant<<<EE, b256, 0, stream>>>(k_w, qw, sw, 127.f);
  k_gemm<<<gg, b256, 0, stream>>>(qx, sx, qw, sw, k_b, 1.f, kbuf, k_hi, k_lo);
  k_rowquant<<<EE, b256, 0, stream>>>(v_w, qw, sw, 127.f);
  k_gemm<<<gg, b256, 0, stream>>>(qx, sx, qw, sw, v_b, 1.f, vbuf, nullptr, nullptr);
  // 3. v = quant_absmax_last(vraw)
  k_quantdq_row<<<TT, b256, 0, stream>>>(vbuf, vbuf);
  // 4. V per-column quant (transposed int store)
  k_init<<<8, b256, 0, stream>>>(sv_bits, imp);
  k_colmax<<<dim3(EE/256, TT/256), b256, 0, stream>>>(vbuf, sv_bits);
  k_vq_transpose<<<dim3(TT/64, EE/64), b256, 0, stream>>>(vbuf, sv_bits, sv, qvT);
  // 5. attention pass 1 (chunked stats -> combine -> chunked column sums)
  k_attn1_stats<<<ga, b256, 0, stream>>>(q_hi, q_lo, k_hi, k_lo, mp, lp);
  k_stats_combine<<<dim3(32,16), dim3(64), 0, stream>>>(mp, lp, m1, il1);
  k_attn1_acc<<<ga, b256, 0, stream>>>(q_hi, q_lo, k_hi, k_lo, m1, il1, partial);
  // 6. top-k per quarter
  k_topk<<<4, dim3(512), 0, stream>>>(partial, imp);
  // 7. mixed K quantization
  k_quant_kmixed<<<TT, b256, 0, stream>>>(kbuf, imp, qkm, skv);
  // 8. attention pass 2 (chunked flash) + combine
  k_attn2<<<ga, b256, 0, stream>>>(q_hi, q_lo, qkm, skv, qvT, sv, ctx, mp2, lp2, Opart);
  k_attn2_combine<<<dim3(24,16), b256, 0, stream>>>(mp2, lp2, Opart, sv, ctx);
  // 9. output projection
  k_rowquant<<<TT, b256, 0, stream>>>(ctx, qctx, sctx, 127.f);
  k_rowquant<<<EE, b256, 0, stream>>>(o_w, qw, sw, 127.f);
  k_gemm<<<gg, b256, 0, stream>>>(qctx, sctx, qw, sw, o_b, 1.f, (float*)d_out, nullptr, nullptr);
}

// Round 3
// 549.441 us; speedup vs baseline: 1.9865x; 1.2856x over previous
//
#include <hip/hip_runtime.h>
#include <stdint.h>

#define TT 2048
#define EE 2048
#define HH 16
#define DD 128

static constexpr float F_EPS = 1e-5f;
static constexpr float F_SCALING = (float)0.08838834764831845; // 128^-0.5

using f32x4  = __attribute__((ext_vector_type(4))) float;
using bf16x8 = __attribute__((ext_vector_type(8))) short;
using u16x8  = __attribute__((ext_vector_type(8))) unsigned short;

#define MFMA_BF16(a,b,c) __builtin_amdgcn_mfma_f32_16x16x32_bf16((a),(b),(c),0,0,0)

#define GLD16(gp, lp) __builtin_amdgcn_global_load_lds( \
    (__attribute__((address_space(1))) void*)(unsigned long long)(gp), \
    (__attribute__((address_space(3))) void*)(lp), 16, 0, 0)

__device__ __forceinline__ unsigned short f2bf(float x){
  unsigned u = __float_as_uint(x);
  u = (u + 0x7FFFu + ((u >> 16) & 1u)) >> 16;
  return (unsigned short)u;
}
__device__ __forceinline__ float bf2f(unsigned short h){
  return __uint_as_float(((unsigned)h) << 16);
}

// chunk enumeration: per head, 80 blocks cover the causal triangle with <=8 tiles each
__device__ __forceinline__ void cid_map(int cid, int& qt, int& ch, int& nc){
  if (cid < 8)       { qt = cid;                ch = 0;            nc = 1; }
  else if (cid < 24) { qt = 8  + ((cid-8)>>1);  ch = (cid-8)&1;    nc = 2; }
  else if (cid < 48) { qt = 16 + (cid-24)/3;    ch = (cid-24)%3;   nc = 3; }
  else               { qt = 24 + ((cid-48)>>2); ch = (cid-48)&3;   nc = 4; }
}
__device__ __forceinline__ int aoff(int qt){
  return (qt<16) ? 2*(qt-8) : ((qt<24) ? 16+3*(qt-16) : 40+4*(qt-24));
}

// ---- LDS staging with XOR swizzle (byte ^= (row&7)<<4) on global src + reads
__device__ __forceinline__ void stage_k64x128(const unsigned short* gbase, unsigned short* lds, int tid){
  const char* gb = (const char*)gbase;
  char* lb = (char*)lds;
  #pragma unroll
  for (int i=0;i<4;i++){
    const int idx = i*256 + tid;
    const int r = idx >> 4, c = idx & 15;
    GLD16(gb + (size_t)r*(EE*2) + (unsigned)((c*16) ^ ((r&7)<<4)), lb + idx*16);
  }
}
__device__ __forceinline__ void stage_v128x64(const unsigned short* gbase, unsigned short* lds, int tid){
  const char* gb = (const char*)gbase;
  char* lb = (char*)lds;
  #pragma unroll
  for (int i=0;i<4;i++){
    const int idx = i*256 + tid;
    const int r = idx >> 3, c = idx & 7;
    GLD16(gb + (size_t)r*(TT*2) + (unsigned)((c*16) ^ ((r&7)<<4)), lb + idx*16);
  }
}
__device__ __forceinline__ bf16x8 frag_k(const unsigned short* lds, int kr, int dbyte){
  return *(const bf16x8*)((const char*)lds + kr*256 + (dbyte ^ ((kr&7)<<4)));
}
__device__ __forceinline__ bf16x8 frag_v(const unsigned short* lds, int dr, int kbyte){
  return *(const bf16x8*)((const char*)lds + dr*128 + (kbyte ^ ((dr&7)<<4)));
}

// ---------------- row-wise quantization kernels ----------------
__global__ __launch_bounds__(256) void k_rowquant(
    const float* __restrict__ in, unsigned short* __restrict__ outq,
    float* __restrict__ outs, float qmax)
{
  const int row = blockIdx.x;
  const int tid = threadIdx.x;
  const float* r = in + (size_t)row * EE;
  float x[8];
  {
    const f32x4 a = *(const f32x4*)(r + tid*8);
    const f32x4 b = *(const f32x4*)(r + tid*8 + 4);
    x[0]=a[0]; x[1]=a[1]; x[2]=a[2]; x[3]=a[3];
    x[4]=b[0]; x[5]=b[1]; x[6]=b[2]; x[7]=b[3];
  }
  float am = 0.f;
  #pragma unroll
  for (int j=0;j<8;j++) am = fmaxf(am, fabsf(x[j]));
  #pragma unroll
  for (int o=1;o<64;o<<=1) am = fmaxf(am, __shfl_xor(am, o));
  __shared__ float red[4];
  if ((tid&63)==0) red[tid>>6] = am;
  __syncthreads();
  am = fmaxf(fmaxf(red[0],red[1]), fmaxf(red[2],red[3]));
  const float s = fmaxf(am, F_EPS) / qmax;
  if (tid==0) outs[row] = s;
  u16x8 qv;
  #pragma unroll
  for (int j=0;j<8;j++) qv[j] = f2bf(rintf(x[j]/s));
  *(u16x8*)(outq + (size_t)row*EE + tid*8) = qv;
}

__global__ __launch_bounds__(256) void k_quantdq_row(
    const float* __restrict__ in, float* __restrict__ out)
{
  const int row = blockIdx.x;
  const int tid = threadIdx.x;
  const float* r = in + (size_t)row * EE;
  float x[8];
  {
    const f32x4 a = *(const f32x4*)(r + tid*8);
    const f32x4 b = *(const f32x4*)(r + tid*8 + 4);
    x[0]=a[0]; x[1]=a[1]; x[2]=a[2]; x[3]=a[3];
    x[4]=b[0]; x[5]=b[1]; x[6]=b[2]; x[7]=b[3];
  }
  float am = 0.f;
  #pragma unroll
  for (int j=0;j<8;j++) am = fmaxf(am, fabsf(x[j]));
  #pragma unroll
  for (int o=1;o<64;o<<=1) am = fmaxf(am, __shfl_xor(am, o));
  __shared__ float red[4];
  if ((tid&63)==0) red[tid>>6] = am;
  __syncthreads();
  am = fmaxf(fmaxf(red[0],red[1]), fmaxf(red[2],red[3]));
  const float s = fmaxf(am, F_EPS) / 127.f;
  f32x4 o0, o1;
  o0[0]=rintf(x[0]/s)*s; o0[1]=rintf(x[1]/s)*s; o0[2]=rintf(x[2]/s)*s; o0[3]=rintf(x[3]/s)*s;
  o1[0]=rintf(x[4]/s)*s; o1[1]=rintf(x[5]/s)*s; o1[2]=rintf(x[6]/s)*s; o1[3]=rintf(x[7]/s)*s;
  *(f32x4*)(out + (size_t)row*EE + tid*8)     = o0;
  *(f32x4*)(out + (size_t)row*EE + tid*8 + 4) = o1;
}

__global__ __launch_bounds__(256) void k_quant_kmixed(
    const float* __restrict__ kin, const int* __restrict__ imp,
    unsigned short* __restrict__ qkm, float* __restrict__ sk)
{
  const int row = blockIdx.x;
  const int tid = threadIdx.x;
  const float* r = kin + (size_t)row * EE;
  float x[8];
  {
    const f32x4 a = *(const f32x4*)(r + tid*8);
    const f32x4 b = *(const f32x4*)(r + tid*8 + 4);
    x[0]=a[0]; x[1]=a[1]; x[2]=a[2]; x[3]=a[3];
    x[4]=b[0]; x[5]=b[1]; x[6]=b[2]; x[7]=b[3];
  }
  float am = 0.f;
  #pragma unroll
  for (int j=0;j<8;j++) am = fmaxf(am, fabsf(x[j]));
  #pragma unroll
  for (int o=1;o<64;o<<=1) am = fmaxf(am, __shfl_xor(am, o));
  __shared__ float red[4];
  if ((tid&63)==0) red[tid>>6] = am;
  __syncthreads();
  am = fmaxf(fmaxf(red[0],red[1]), fmaxf(red[2],red[3]));
  float s;
  if (imp[row]) s = fmaxf(am / 127.f, F_EPS);
  else          s = fmaxf(am, F_EPS) / 7.f;
  if (tid==0) sk[row] = s;
  u16x8 qv;
  #pragma unroll
  for (int j=0;j<8;j++) qv[j] = f2bf(rintf(x[j]/s));
  *(u16x8*)(qkm + (size_t)row*EE + tid*8) = qv;
}

// ---------------- GEMM (128x128 tile, BK=64) ----------------
__global__ __launch_bounds__(256) void k_gemm(
    const unsigned short* __restrict__ Aq, const float* __restrict__ sa,
    const unsigned short* __restrict__ Bq, const float* __restrict__ sb,
    const float* __restrict__ bias, float post_scale,
    float* __restrict__ Cout, unsigned short* __restrict__ Hout,
    unsigned short* __restrict__ Lout)
{
  __shared__ unsigned short lA[128*64];
  __shared__ unsigned short lB[128*64];
  const int tid = threadIdx.x;
  const int bm = blockIdx.y, bn = blockIdx.x;
  const int lane = tid & 63, w = tid >> 6;
  const int wr = w >> 1, wc = w & 1;
  const int rA = tid >> 3;
  const int cA = (tid & 7) * 8;
  f32x4 acc[4][4];
  const f32x4 FZ = {0.f,0.f,0.f,0.f};
  #pragma unroll
  for (int i=0;i<4;i++)
    #pragma unroll
    for (int j=0;j<4;j++) acc[i][j] = FZ;

  const unsigned short* gA0 = Aq + (size_t)(bm*128 + rA)*EE + cA;
  const unsigned short* gB0 = Bq + (size_t)(bn*128 + rA)*EE + cA;
  unsigned short* lA0 = lA + tid*8;
  unsigned short* lB0 = lB + tid*8;

  for (int k0 = 0; k0 < EE; k0 += 64) {
    #pragma unroll
    for (int i=0;i<4;i++) GLD16(gA0 + (size_t)i*32*EE + k0, lA0 + i*2048);
    #pragma unroll
    for (int i=0;i<4;i++) GLD16(gB0 + (size_t)i*32*EE + k0, lB0 + i*2048);
    __syncthreads();
    #pragma unroll
    for (int kk=0;kk<2;kk++){
      bf16x8 af[4], bfr[4];
      #pragma unroll
      for (int mi=0;mi<4;mi++)
        af[mi] = *(const bf16x8*)(lA + (wr*64 + mi*16 + (lane&15))*64 + kk*32 + (lane>>4)*8);
      #pragma unroll
      for (int ni=0;ni<4;ni++)
        bfr[ni] = *(const bf16x8*)(lB + (wc*64 + ni*16 + (lane&15))*64 + kk*32 + (lane>>4)*8);
      #pragma unroll
      for (int mi=0;mi<4;mi++)
        #pragma unroll
        for (int ni=0;ni<4;ni++)
          acc[mi][ni] = MFMA_BF16(af[mi], bfr[ni], acc[mi][ni]);
    }
    __syncthreads();
  }
  const int row0 = bm*128 + wr*64;
  const int col0 = bn*128 + wc*64;
  #pragma unroll
  for (int mi=0;mi<4;mi++){
    #pragma unroll
    for (int r=0;r<4;r++){
      const int row = row0 + mi*16 + (lane>>4)*4 + r;
      const float sav = sa[row];
      #pragma unroll
      for (int ni=0;ni<4;ni++){
        const int col = col0 + ni*16 + (lane&15);
        const float v = (acc[mi][ni][r]*sav*sb[col] + bias[col]) * post_scale;
        if (Cout) Cout[(size_t)row*EE + col] = v;
        if (Hout){
          const unsigned short hh = f2bf(v);
          Hout[(size_t)row*EE + col] = hh;
          Lout[(size_t)row*EE + col] = f2bf(v - bf2f(hh));
        }
      }
    }
  }
}

// ---------------- V per-column quant ----------------
__global__ void k_init(unsigned* __restrict__ sv_bits, int* __restrict__ imp)
{
  const int i = blockIdx.x*256 + threadIdx.x;
  if (i < EE) sv_bits[i] = 0u;
  if (i < TT) imp[i] = 0;
}

__global__ __launch_bounds__(256) void k_colmax(
    const float* __restrict__ v, unsigned* __restrict__ sv_bits)
{
  const int e = blockIdx.x*256 + threadIdx.x;
  const int t0 = blockIdx.y*256;
  float am = 0.f;
  for (int t=t0; t<t0+256; ++t) am = fmaxf(am, fabsf(v[(size_t)t*EE + e]));
  atomicMax(sv_bits + e, __float_as_uint(am));
}

__global__ __launch_bounds__(256) void k_vq_transpose(
    const float* __restrict__ v, const unsigned* __restrict__ sv_bits,
    float* __restrict__ sv, unsigned short* __restrict__ qvT)
{
  __shared__ unsigned short tile[64][66];
  const int t0 = blockIdx.x*64, e0 = blockIdx.y*64;
  const int tid = threadIdx.x;
  {
    const int ee = tid & 63, tb = (tid>>6)*16;
    const float sve = fmaxf(__uint_as_float(sv_bits[e0+ee]), F_EPS) / 127.f;
    for (int i=0;i<16;i++)
      tile[tb+i][ee] = f2bf(rintf(v[(size_t)(t0+tb+i)*EE + e0+ee] / sve));
  }
  if (blockIdx.x==0 && tid<64)
    sv[e0+tid] = fmaxf(__uint_as_float(sv_bits[e0+tid]), F_EPS) / 127.f;
  __syncthreads();
  {
    const int ttl = tid & 63, ebl = (tid>>6)*16;
    for (int i=0;i<16;i++)
      qvT[(size_t)(e0+ebl+i)*TT + t0+ttl] = tile[ttl][ebl+i];
  }
}

// ---------------- attention pass 1: chunked softmax stats ----------------
__global__ __launch_bounds__(256) void k_attn1_stats(
    const unsigned short* __restrict__ qh, const unsigned short* __restrict__ ql,
    const unsigned short* __restrict__ kh, const unsigned short* __restrict__ kl,
    float* __restrict__ mp, float* __restrict__ lp)
{
  __shared__ unsigned short lKh[64*128];
  __shared__ unsigned short lKl[64*128];
  const int h = blockIdx.y, cid = blockIdx.x;
  int qt, ch, nc; cid_map(cid, qt, ch, nc);
  const int per = (qt + nc)/nc;
  const int s0 = ch*per, s1 = min(s0+per-1, qt);
  const int tid = threadIdx.x, w = tid>>6, lane = tid&63;
  const int row_base = qt*64 + w*16, lrow = (lane>>4)*4;
  bf16x8 qhf[4], qlf[4];
  {
    const size_t qo = (size_t)(row_base + (lane&15))*EE + h*DD + (lane>>4)*8;
    #pragma unroll
    for (int kc=0;kc<4;kc++){
      qhf[kc] = *(const bf16x8*)(qh + qo + kc*32);
      qlf[kc] = *(const bf16x8*)(ql + qo + kc*32);
    }
  }
  float m_r[4], l_r[4];
  #pragma unroll
  for (int r=0;r<4;r++){ m_r[r] = -3.0e38f; l_r[r] = 0.f; }
  stage_k64x128(kh + (size_t)(s0*64)*EE + h*DD, lKh, tid);
  stage_k64x128(kl + (size_t)(s0*64)*EE + h*DD, lKl, tid);
  for (int st=s0; st<=s1; ++st){
    __syncthreads();
    f32x4 S[4];
    #pragma unroll
    for (int n=0;n<4;n++){
      f32x4 a = {0.f,0.f,0.f,0.f};
      const int kr = n*16 + (lane&15);
      #pragma unroll
      for (int kc=0;kc<4;kc++){
        const int db = kc*64 + (lane>>4)*16;
        const bf16x8 khf = frag_k(lKh, kr, db);
        const bf16x8 klf = frag_k(lKl, kr, db);
        a = MFMA_BF16(qhf[kc], khf, a);
        a = MFMA_BF16(qlf[kc], khf, a);
        a = MFMA_BF16(qhf[kc], klf, a);
      }
      S[n] = a;
    }
    __syncthreads();
    if (st < s1){
      stage_k64x128(kh + (size_t)((st+1)*64)*EE + h*DD, lKh, tid);
      stage_k64x128(kl + (size_t)((st+1)*64)*EE + h*DD, lKl, tid);
    }
    #pragma unroll
    for (int r=0;r<4;r++){
      const int row = row_base + lrow + r;
      float tmax = -3.0e38f;
      #pragma unroll
      for (int n=0;n<4;n++){
        const int col = st*64 + n*16 + (lane&15);
        tmax = fmaxf(tmax, (col<=row) ? S[n][r] : -3.0e38f);
      }
      tmax = fmaxf(tmax, __shfl_xor(tmax,1));
      tmax = fmaxf(tmax, __shfl_xor(tmax,2));
      tmax = fmaxf(tmax, __shfl_xor(tmax,4));
      tmax = fmaxf(tmax, __shfl_xor(tmax,8));
      const float nm = fmaxf(m_r[r], tmax);
      float rs = 0.f;
      #pragma unroll
      for (int n=0;n<4;n++){
        const int col = st*64 + n*16 + (lane&15);
        rs += (col<=row) ? __expf(S[n][r]-nm) : 0.f;
      }
      rs += __shfl_xor(rs,1); rs += __shfl_xor(rs,2);
      rs += __shfl_xor(rs,4); rs += __shfl_xor(rs,8);
      l_r[r] = l_r[r]*__expf(m_r[r]-nm) + rs;
      m_r[r] = nm;
    }
  }
  if ((lane&15)==0){
    const int slot = (h*80 + cid)*64;
    #pragma unroll
    for (int r=0;r<4;r++){
      mp[slot + w*16 + lrow + r] = m_r[r];
      lp[slot + w*16 + lrow + r] = l_r[r];
    }
  }
}

__global__ __launch_bounds__(64) void k_stats_combine(
    const float* __restrict__ mp, const float* __restrict__ lp,
    float* __restrict__ m1, float* __restrict__ il1)
{
  const int qt = blockIdx.x, h = blockIdx.y, r = threadIdx.x;
  const int nc  = (qt<8)?1:((qt<16)?2:((qt<24)?3:4));
  const int off = (qt<8)?qt:((qt<16)?8+2*(qt-8):((qt<24)?24+3*(qt-16):48+4*(qt-24)));
  const int base = (h*80 + off)*64 + r;
  float m = mp[base];
  for (int i=1;i<nc;i++) m = fmaxf(m, mp[base + i*64]);
  float l = 0.f;
  for (int i=0;i<nc;i++) l += lp[base + i*64]*__expf(mp[base + i*64]-m);
  m1[h*TT + qt*64 + r] = m;
  il1[h*TT + qt*64 + r] = 1.f/l;
}

// ---------------- attention pass 1b: chunked per-key prob column sums ----------------
__global__ __launch_bounds__(256) void k_attn1_acc(
    const unsigned short* __restrict__ qh, const unsigned short* __restrict__ ql,
    const unsigned short* __restrict__ kh, const unsigned short* __restrict__ kl,
    const float* __restrict__ m1, const float* __restrict__ il1,
    float* __restrict__ partial)
{
  __shared__ unsigned short lKh[64*128];
  __shared__ unsigned short lKl[64*128];
  __shared__ float accw[4][512];
  const int h = blockIdx.y, cid = blockIdx.x;
  int qt, ch, nc; cid_map(cid, qt, ch, nc);
  const int per = (qt + nc)/nc;
  const int s0 = ch*per, s1 = min(s0+per-1, qt);
  const int tid = threadIdx.x, w = tid>>6, lane = tid&63;
  const int row_base = qt*64 + w*16, lrow = (lane>>4)*4;
  bf16x8 qhf[4], qlf[4];
  {
    const size_t qo = (size_t)(row_base + (lane&15))*EE + h*DD + (lane>>4)*8;
    #pragma unroll
    for (int kc=0;kc<4;kc++){
      qhf[kc] = *(const bf16x8*)(qh + qo + kc*32);
      qlf[kc] = *(const bf16x8*)(ql + qo + kc*32);
    }
  }
  float m_r[4], il_r[4];
  #pragma unroll
  for (int r=0;r<4;r++){
    const int row = row_base + lrow + r;
    m_r[r] = m1[h*TT + row]; il_r[r] = il1[h*TT + row];
  }
  stage_k64x128(kh + (size_t)(s0*64)*EE + h*DD, lKh, tid);
  stage_k64x128(kl + (size_t)(s0*64)*EE + h*DD, lKl, tid);
  for (int st=s0; st<=s1; ++st){
    __syncthreads();
    f32x4 S[4];
    #pragma unroll
    for (int n=0;n<4;n++){
      f32x4 a = {0.f,0.f,0.f,0.f};
      const int kr = n*16 + (lane&15);
      #pragma unroll
      for (int kc=0;kc<4;kc++){
        const int db = kc*64 + (lane>>4)*16;
        const bf16x8 khf = frag_k(lKh, kr, db);
        const bf16x8 klf = frag_k(lKl, kr, db);
        a = MFMA_BF16(qhf[kc], khf, a);
        a = MFMA_BF16(qlf[kc], khf, a);
        a = MFMA_BF16(qhf[kc], klf, a);
      }
      S[n] = a;
    }
    __syncthreads();
    if (st < s1){
      stage_k64x128(kh + (size_t)((st+1)*64)*EE + h*DD, lKh, tid);
      stage_k64x128(kl + (size_t)((st+1)*64)*EE + h*DD, lKl, tid);
    }
    #pragma unroll
    for (int n=0;n<4;n++){
      const int col = st*64 + n*16 + (lane&15);
      float cs = 0.f;
      #pragma unroll
      for (int r=0;r<4;r++){
        const int row = row_base + lrow + r;
        cs += (col<=row) ? __expf(S[n][r]-m_r[r])*il_r[r] : 0.f;
      }
      cs += __shfl_xor(cs,16);
      cs += __shfl_xor(cs,32);
      if (lane < 16) accw[w][(st-s0)*64 + n*16 + lane] = cs;
    }
  }
  __syncthreads();
  const int ncols = (s1-s0+1)*64;
  float* dst = partial + (size_t)(h*32+qt)*TT + s0*64;
  for (int i=tid; i<ncols; i+=256)
    dst[i] = accw[0][i]+accw[1][i]+accw[2][i]+accw[3][i];
}

// ---------------- acc reduce + rank-count top-51 selection ----------------
// k_accsum: per-head sum over valid qt tiles. grid (TT/256, HH).
__global__ __launch_bounds__(256) void k_accsum(
    const float* __restrict__ partial, float* __restrict__ acc16)
{
  const int s = blockIdx.x*256 + threadIdx.x;
  const int hh = blockIdx.y;
  const int tmin = s >> 6;
  float a = 0.f;
  for (int qt=tmin; qt<32; ++qt)
    a += partial[(size_t)(hh*32+qt)*TT + s];
  acc16[hh*TT + s] = a;
}

// k_select: rank-count top-51 per 512-quarter; no barriers in the count loop.
__global__ __launch_bounds__(512) void k_select(
    const float* __restrict__ acc16, int* __restrict__ imp)
{
  __shared__ float vals[512];
  const int tid = threadIdx.x;
  const int s = blockIdx.x*512 + tid;
  float a = 0.f;
  #pragma unroll
  for (int hh=0; hh<16; ++hh) a += acc16[hh*TT + s];
  a = a / (float)(TT - s) / 16.f;
  vals[tid] = a;
  __syncthreads();
  int rank = 0;
  for (int j=0; j<512; ++j){
    const float vj = vals[j];
    rank += (vj > a) || (vj == a && j < tid);
  }
  imp[s] = (rank < 51) ? 1 : 0;
}

// ---------------- attention pass 2: chunked flash with quantized K/V ----------------
__global__ __launch_bounds__(256) void k_attn2(
    const unsigned short* __restrict__ qh, const unsigned short* __restrict__ ql,
    const unsigned short* __restrict__ qkm, const float* __restrict__ sk,
    const unsigned short* __restrict__ qvT, const float* __restrict__ sv,
    float* __restrict__ ctx, float* __restrict__ mp2, float* __restrict__ lp2,
    unsigned short* __restrict__ Opart)
{
  __shared__ unsigned short lK[64*128];
  __shared__ unsigned short lV[128*64];
  __shared__ unsigned short Ph[4][16*64];
  const int h = blockIdx.y, cid = blockIdx.x;
  int qt, ch, nc; cid_map(cid, qt, ch, nc);
  const int per = (qt + nc)/nc;
  const int s0 = ch*per, s1 = min(s0+per-1, qt);
  const int tid = threadIdx.x, w = tid>>6, lane = tid&63;
  const int row_base = qt*64 + w*16, lrow = (lane>>4)*4;
  bf16x8 qhf[4], qlf[4];
  {
    const size_t qo = (size_t)(row_base + (lane&15))*EE + h*DD + (lane>>4)*8;
    #pragma unroll
    for (int kc=0;kc<4;kc++){
      qhf[kc] = *(const bf16x8*)(qh + qo + kc*32);
      qlf[kc] = *(const bf16x8*)(ql + qo + kc*32);
    }
  }
  float m_r[4], l_r[4];
  f32x4 oa[8];
  const f32x4 FZ = {0.f,0.f,0.f,0.f};
  #pragma unroll
  for (int r=0;r<4;r++){ m_r[r] = -3.0e38f; l_r[r] = 0.f; }
  #pragma unroll
  for (int d8=0; d8<8; ++d8) oa[d8] = FZ;

  stage_k64x128(qkm + (size_t)(s0*64)*EE + h*DD, lK, tid);
  stage_v128x64(qvT + (size_t)(h*DD)*TT + s0*64, lV, tid);

  for (int st=s0; st<=s1; ++st){
    __syncthreads();
    f32x4 S[4];
    #pragma unroll
    for (int n=0;n<4;n++){
      f32x4 a = {0.f,0.f,0.f,0.f};
      const int kr = n*16 + (lane&15);
      #pragma unroll
      for (int kc=0;kc<4;kc++){
        const int db = kc*64 + (lane>>4)*16;
        const bf16x8 kf = frag_k(lK, kr, db);
        a = MFMA_BF16(qhf[kc], kf, a);
        a = MFMA_BF16(qlf[kc], kf, a);
      }
      S[n] = a * sk[st*64 + n*16 + (lane&15)];
    }
    float p[4][4]; float scale[4];
    #pragma unroll
    for (int r=0;r<4;r++){
      const int row = row_base + lrow + r;
      float tmax = -3.0e38f;
      #pragma unroll
      for (int n=0;n<4;n++){
        const int col = st*64 + n*16 + (lane&15);
        tmax = fmaxf(tmax, (col<=row) ? S[n][r] : -3.0e38f);
      }
      tmax = fmaxf(tmax, __shfl_xor(tmax,1));
      tmax = fmaxf(tmax, __shfl_xor(tmax,2));
      tmax = fmaxf(tmax, __shfl_xor(tmax,4));
      tmax = fmaxf(tmax, __shfl_xor(tmax,8));
      const float nm = fmaxf(m_r[r], tmax);
      scale[r] = __expf(m_r[r]-nm);
      float rs = 0.f;
      #pragma unroll
      for (int n=0;n<4;n++){
        const int col = st*64 + n*16 + (lane&15);
        const float pv = (col<=row) ? __expf(S[n][r]-nm) : 0.f;
        p[n][r] = pv; rs += pv;
      }
      rs += __shfl_xor(rs,1); rs += __shfl_xor(rs,2);
      rs += __shfl_xor(rs,4); rs += __shfl_xor(rs,8);
      l_r[r] = l_r[r]*scale[r] + rs;
      m_r[r] = nm;
    }
    #pragma unroll
    for (int d8=0; d8<8; ++d8){
      #pragma unroll
      for (int r=0;r<4;r++) oa[d8][r] *= scale[r];
    }
    #pragma unroll
    for (int n=0;n<4;n++){
      #pragma unroll
      for (int r=0;r<4;r++){
        const int row = lrow + r;
        *(unsigned short*)((char*)&Ph[w][0] + row*128 +
            ((((n*16 + (lane&15))*2)) ^ ((row&7)<<4))) = f2bf(p[n][r]);
      }
    }
    __syncthreads();
    bf16x8 pah[2];
    #pragma unroll
    for (int kc=0;kc<2;kc++){
      const int rr = lane&15;
      const int cb = kc*64 + (lane>>4)*16;
      pah[kc] = *(const bf16x8*)((const char*)&Ph[w][0] + rr*128 + (cb ^ ((rr&7)<<4)));
    }
    #pragma unroll
    for (int d8=0; d8<8; ++d8){
      const int dr = d8*16 + (lane&15);
      const int kb = (lane>>4)*16;
      const bf16x8 v0 = frag_v(lV, dr, kb);
      const bf16x8 v1 = frag_v(lV, dr, kb + 64);
      oa[d8] = MFMA_BF16(pah[0], v0, oa[d8]);
      oa[d8] = MFMA_BF16(pah[1], v1, oa[d8]);
    }
    __syncthreads();
    if (st < s1){
      stage_k64x128(qkm + (size_t)((st+1)*64)*EE + h*DD, lK, tid);
      stage_v128x64(qvT + (size_t)(h*DD)*TT + (st+1)*64, lV, tid);
    }
  }
  if (nc == 1){
    #pragma unroll
    for (int d8=0; d8<8; ++d8){
      const float sve = sv[h*DD + d8*16 + (lane&15)];
      #pragma unroll
      for (int r=0;r<4;r++){
        const int row = row_base + lrow + r;
        ctx[(size_t)row*EE + h*DD + d8*16 + (lane&15)] = oa[d8][r]*sve/l_r[r];
      }
    }
  } else {
    const int slot = h*72 + aoff(qt) + ch;
    if ((lane&15)==0){
      #pragma unroll
      for (int r=0;r<4;r++){
        mp2[slot*64 + w*16 + lrow + r] = m_r[r];
        lp2[slot*64 + w*16 + lrow + r] = l_r[r];
      }
    }
    #pragma unroll
    for (int d8=0; d8<8; ++d8){
      #pragma unroll
      for (int r=0;r<4;r++)
        Opart[(size_t)slot*8192 + (w*16 + lrow + r)*128 + d8*16 + (lane&15)] = f2bf(oa[d8][r]);
    }
  }
}

__global__ __launch_bounds__(256) void k_attn2_combine(
    const float* __restrict__ mp2, const float* __restrict__ lp2,
    const unsigned short* __restrict__ Opart, const float* __restrict__ sv,
    float* __restrict__ ctx)
{
  __shared__ float wsc[4][64];
  __shared__ float lst[64];
  const int qt = 8 + blockIdx.x, h = blockIdx.y;
  const int nc = (qt + 8) >> 3;
  const int base = h*72 + aoff(qt);
  const int tid = threadIdx.x;
  if (tid < 64){
    float m = mp2[base*64 + tid];
    for (int i=1;i<nc;i++) m = fmaxf(m, mp2[(base+i)*64 + tid]);
    float l = 0.f;
    for (int i=0;i<nc;i++){
      const float wv = __expf(mp2[(base+i)*64 + tid] - m);
      wsc[i][tid] = wv;
      l += lp2[(base+i)*64 + tid]*wv;
    }
    lst[tid] = 1.f/l;
  }
  __syncthreads();
  #pragma unroll
  for (int e=0;e<32;e++){
    const int idx = e*256 + tid;
    const int row = idx>>7, d = idx&127;
    float a = 0.f;
    for (int i=0;i<nc;i++)
      a += bf2f(Opart[(size_t)(base+i)*8192 + idx]) * wsc[i][row];
    ctx[(size_t)(qt*64+row)*EE + h*DD + d] = a * sv[h*DD + d] * lst[row];
  }
}

// ---------------- host launch ----------------
extern "C" void kernel_launch(void* const* d_in, const int* in_sizes, int n_in,
                              void* d_out, int out_size, void* d_ws, size_t ws_size,
                              hipStream_t stream)
{
  (void)in_sizes; (void)n_in; (void)out_size; (void)ws_size;
  const float* hs  = (const float*)d_in[0];
  const float* q_w = (const float*)d_in[2];
  const float* q_b = (const float*)d_in[3];
  const float* k_w = (const float*)d_in[4];
  const float* k_b = (const float*)d_in[5];
  const float* v_w = (const float*)d_in[6];
  const float* v_b = (const float*)d_in[7];
  const float* o_w = (const float*)d_in[8];
  const float* o_b = (const float*)d_in[9];

  char* ws = (char*)d_ws;
  const size_t MB = 1ull<<20;
  unsigned short* qx   = (unsigned short*)(ws + 0*MB);    // 8 MB; reused: qctx
  unsigned short* qw   = (unsigned short*)(ws + 8*MB);    // 8 MB; dead between V-GEMM and o_w quant
  unsigned short* q_hi = (unsigned short*)(ws + 16*MB);   // 8 MB
  unsigned short* q_lo = (unsigned short*)(ws + 24*MB);   // 8 MB
  float*          kbuf = (float*)(ws + 32*MB);            // 16 MB; reused: ctx
  unsigned short* k_hi = (unsigned short*)(ws + 48*MB);   // 8 MB; reused: qkm
  unsigned short* k_lo = (unsigned short*)(ws + 56*MB);   // 8 MB
  float*          vbuf = (float*)(ws + 64*MB);            // 16 MB; dead after V quant
  float*          partial = (float*)(ws + 80*MB);         // 4 MB; dead after accsum
  unsigned short* qvT  = (unsigned short*)(ws + 84*MB);   // 8 MB
  char*           sm   = ws + 92*MB;
  float*    sx   = (float*)(sm + 0);
  float*    sw   = (float*)(sm + 16*1024);
  float*    m1   = (float*)(sm + 32*1024);
  float*    il1  = (float*)(sm + 168*1024);
  int*      imp  = (int*)(sm + 304*1024);
  float*    skv  = (float*)(sm + 316*1024);
  unsigned* sv_bits = (unsigned*)(sm + 328*1024);
  float*    sv   = (float*)(sm + 340*1024);
  float*    sctx = (float*)(sm + 352*1024);
  // overlays (disjoint lifetimes, stream-ordered):
  float* mp  = (float*)qx;
  float* lp  = mp + 80*16*64;
  float* mp2 = (float*)vbuf;
  float* lp2 = mp2 + 1152*64;
  unsigned short* Opart = (unsigned short*)(ws + 64*MB + 1*MB);
  float* acc16 = (float*)qw;               // 128 KB in dead qw window
  unsigned short* qkm  = k_hi;
  float*          ctx  = kbuf;
  unsigned short* qctx = qx;

  dim3 b256(256);
  dim3 gg(EE/128, TT/128);
  dim3 ga(80, HH);

  // 1. quantize hidden states
  k_rowquant<<<TT, b256, 0, stream>>>(hs, qx, sx, 127.f);
  // 2. Q/K/V projections
  k_rowquant<<<EE, b256, 0, stream>>>(q_w, qw, sw, 127.f);
  k_gemm<<<gg, b256, 0, stream>>>(qx, sx, qw, sw, q_b, F_SCALING, nullptr, q_hi, q_lo);
  k_rowquant<<<EE, b256, 0, stream>>>(k_w, qw, sw, 127.f);
  k_gemm<<<gg, b256, 0, stream>>>(qx, sx, qw, sw, k_b, 1.f, kbuf, k_hi, k_lo);
  k_rowquant<<<EE, b256, 0, stream>>>(v_w, qw, sw, 127.f);
  k_gemm<<<gg, b256, 0, stream>>>(qx, sx, qw, sw, v_b, 1.f, vbuf, nullptr, nullptr);
  // 3. v = quant_absmax_last(vraw)
  k_quantdq_row<<<TT, b256, 0, stream>>>(vbuf, vbuf);
  // 4. V per-column quant (transposed int store)
  k_init<<<8, b256, 0, stream>>>(sv_bits, imp);
  k_colmax<<<dim3(EE/256, TT/256), b256, 0, stream>>>(vbuf, sv_bits);
  k_vq_transpose<<<dim3(TT/64, EE/64), b256, 0, stream>>>(vbuf, sv_bits, sv, qvT);
  // 5. attention pass 1
  k_attn1_stats<<<ga, b256, 0, stream>>>(q_hi, q_lo, k_hi, k_lo, mp, lp);
  k_stats_combine<<<dim3(32,16), dim3(64), 0, stream>>>(mp, lp, m1, il1);
  k_attn1_acc<<<ga, b256, 0, stream>>>(q_hi, q_lo, k_hi, k_lo, m1, il1, partial);
  // 6. reduce + rank-count top-k per quarter
  k_accsum<<<dim3(TT/256, HH), b256, 0, stream>>>(partial, acc16);
  k_select<<<4, dim3(512), 0, stream>>>(acc16, imp);
  // 7. mixed K quantization
  k_quant_kmixed<<<TT, b256, 0, stream>>>(kbuf, imp, qkm, skv);
  // 8. attention pass 2 (chunked flash) + combine
  k_attn2<<<ga, b256, 0, stream>>>(q_hi, q_lo, qkm, skv, qvT, sv, ctx, mp2, lp2, Opart);
  k_attn2_combine<<<dim3(24,16), b256, 0, stream>>>(mp2, lp2, Opart, sv, ctx);
  // 9. output projection
  k_rowquant<<<TT, b256, 0, stream>>>(ctx, qctx, sctx, 127.f);
  k_rowquant<<<EE, b256, 0, stream>>>(o_w, qw, sw, 127.f);
  k_gemm<<<gg, b256, 0, stream>>>(qctx, sctx, qw, sw, o_b, 1.f, (float*)d_out, nullptr, nullptr);
}